// Round 12
// baseline (306.535 us; speedup 1.0000x reference)
//
#include <hip/hip_runtime.h>

#define N_NODES 50000
#define N_EDGES 800000
#define N_GRAPHS 64
#define SCAN_B 256
#define SCAN_NBLK ((N_NODES + SCAN_B - 1) / SCAN_B)   // 196

typedef __attribute__((ext_vector_type(8))) short short8;
typedef __attribute__((ext_vector_type(4))) float floatx4;

// fp32 -> bf16 round-to-nearest-even
__device__ __forceinline__ unsigned short f2bf(float f) {
    unsigned int u = __float_as_uint(f);
    u += 0x7FFFu + ((u >> 16) & 1u);
    return (unsigned short)(u >> 16);
}
__device__ __forceinline__ float bf2f(unsigned short h) {
    return __uint_as_float(((unsigned int)h) << 16);
}
__device__ __forceinline__ float blo(unsigned int u) { return __uint_as_float(u << 16); }
__device__ __forceinline__ float bhi(unsigned int u) { return __uint_as_float(u & 0xffff0000u); }

// ========== prep: zero counts + pooled, cast W2/W3 to packed bf16 B-frag layout ====

__global__ void k_prep(int* counts, float* pooled,
                       const float* __restrict__ W2, const float* __restrict__ W3,
                       unsigned short* Wb2, unsigned short* Wb3) {
    int i = blockIdx.x * blockDim.x + threadIdx.x;
    if (i < N_NODES) counts[i] = 0;
    int j = i - N_NODES;
    if (j >= 0 && j < N_GRAPHS * 128) pooled[j] = 0.0f;
    int k = i - N_NODES - N_GRAPHS * 128;
    if (k >= 0 && k < 64 * 128) {
        int kk = k >> 7, n = k & 127;
        Wb2[(((kk >> 3) * 128) + n) * 8 + (kk & 7)] = f2bf(W2[k]);
    }
    int l = i - N_NODES - N_GRAPHS * 128 - 64 * 128;
    if (l >= 0 && l < 128 * 128) {
        int kk = l >> 7, n = l & 127;
        Wb3[(((kk >> 3) * 128) + n) * 8 + (kk & 7)] = f2bf(W3[l]);
    }
}

// ================= CSR build (real edges only; self-loop analytic) ====
// N_EDGES % 4 == 0: 4 edges per thread, int4 loads.

__global__ void k_hist(const int* __restrict__ dst, int* counts) {
    int e0 = (blockIdx.x * blockDim.x + threadIdx.x) * 4;
    if (e0 >= N_EDGES) return;
    int4 d4 = *(const int4*)(dst + e0);
    atomicAdd(&counts[d4.x], 1);
    atomicAdd(&counts[d4.y], 1);
    atomicAdd(&counts[d4.z], 1);
    atomicAdd(&counts[d4.w], 1);
}

__global__ void k_scan1(const int* __restrict__ counts, int* row_ptr, int* blksum) {
    __shared__ int s[SCAN_B];
    int i = blockIdx.x * SCAN_B + threadIdx.x;
    int c = (i < N_NODES) ? counts[i] : 0;
    s[threadIdx.x] = c;
    __syncthreads();
    for (int off = 1; off < SCAN_B; off <<= 1) {
        int v = (threadIdx.x >= off) ? s[threadIdx.x - off] : 0;
        __syncthreads();
        s[threadIdx.x] += v;
        __syncthreads();
    }
    if (i < N_NODES) row_ptr[i] = s[threadIdx.x] - c;   // exclusive within block
    if (threadIdx.x == SCAN_B - 1) blksum[blockIdx.x] = s[SCAN_B - 1];  // raw block sum
}

// finalize row_ptr (adds exclusive sum of prior raw block sums, computed in-LDS),
// init cursor, dinv = rsqrt(deg = counts+1), xs = x * dinv.  One block == one scan1 block.
__global__ void k_scan3(int* row_ptr, const int* __restrict__ blksum,
                        int* cursor, const int* __restrict__ counts, float* dinv,
                        const float* __restrict__ x, float* __restrict__ xs) {
    __shared__ int s[SCAN_B];
    int t = threadIdx.x;
    int b = blockIdx.x;
    s[t] = (t < b && t < SCAN_NBLK) ? blksum[t] : 0;
    __syncthreads();
    for (int off = SCAN_B / 2; off > 0; off >>= 1) {
        if (t < off) s[t] += s[t + off];
        __syncthreads();
    }
    int offset = s[0];
    int i = b * SCAN_B + t;
    if (i < N_NODES) {
        int v = row_ptr[i] + offset;
        row_ptr[i] = v;
        cursor[i] = v;
        float di = rsqrtf((float)(counts[i] + 1));
        dinv[i] = di;
        xs[i * 3 + 0] = x[i * 3 + 0] * di;
        xs[i * 3 + 1] = x[i * 3 + 1] * di;
        xs[i * 3 + 2] = x[i * 3 + 2] * di;
    }
    if (i == 0) row_ptr[N_NODES] = N_EDGES;
}

// scatter srcs into CSR slots; nontemporal stores avoid L2 line-migration churn
__global__ void k_fill(const int* __restrict__ src, const int* __restrict__ dst,
                       int* cursor, int* csr_src) {
    int e0 = (blockIdx.x * blockDim.x + threadIdx.x) * 4;
    if (e0 >= N_EDGES) return;
    int4 s4 = *(const int4*)(src + e0);
    int4 d4 = *(const int4*)(dst + e0);
    int p0 = atomicAdd(&cursor[d4.x], 1);
    int p1 = atomicAdd(&cursor[d4.y], 1);
    int p2 = atomicAdd(&cursor[d4.z], 1);
    int p3 = atomicAdd(&cursor[d4.w], 1);
    __builtin_nontemporal_store(s4.x, &csr_src[p0]);
    __builtin_nontemporal_store(s4.y, &csr_src[p1]);
    __builtin_nontemporal_store(s4.z, &csr_src[p2]);
    __builtin_nontemporal_store(s4.w, &csr_src[p3]);
}

// ================= layer 1: agg width 3 + small GEMM ==================

__global__ void k_agg3(const float* __restrict__ xs, const int* __restrict__ row_ptr,
                       const int* __restrict__ csr_src, const float* __restrict__ dinv,
                       float* __restrict__ out) {
    int n = blockIdx.x * blockDim.x + threadIdx.x;
    if (n >= N_NODES) return;
    int lo = row_ptr[n], hi = row_ptr[n + 1];
    float a0 = xs[n * 3 + 0], a1 = xs[n * 3 + 1], a2 = xs[n * 3 + 2];
    for (int i = lo; i < hi; ++i) {
        int s = csr_src[i];
        a0 += xs[s * 3 + 0];
        a1 += xs[s * 3 + 1];
        a2 += xs[s * 3 + 2];
    }
    float din = dinv[n];
    out[n * 3 + 0] = a0 * din;
    out[n * 3 + 1] = a1 * din;
    out[n * 3 + 2] = a2 * din;
}

template<int IN_W, int OUT_W, int NPB>
__global__ void k_node_gemm(const float* __restrict__ h, const float* __restrict__ W,
                            const float* __restrict__ b, const float* __restrict__ dinv,
                            unsigned short* __restrict__ hb) {
    __shared__ float rows[NPB][IN_W];
    int n0 = blockIdx.x * NPB;
    int j = threadIdx.x;                         // blockDim.x == OUT_W
    for (int t = j; t < NPB * IN_W; t += OUT_W) {
        int m = t / IN_W, k = t - m * IN_W;
        int n = n0 + m;
        rows[m][k] = (n < N_NODES) ? h[(size_t)n * IN_W + k] : 0.0f;
    }
    __syncthreads();
    float acc[NPB];
    float bj = b[j];
#pragma unroll
    for (int m = 0; m < NPB; ++m) acc[m] = bj;
#pragma unroll
    for (int k = 0; k < IN_W; ++k) {
        float wk = W[k * OUT_W + j];
#pragma unroll
        for (int m = 0; m < NPB; ++m) acc[m] += rows[m][k] * wk;
    }
#pragma unroll
    for (int m = 0; m < NPB; ++m) {
        int n = n0 + m;
        if (n < N_NODES)
            hb[(size_t)n * OUT_W + j] = f2bf(fmaxf(acc[m], 0.0f) * dinv[n]);
    }
}

// ================= aggregation (wave per node, multi-row dwordx4 gathers) =========

// width 64: row = 128 B = 8 chunks x 16 B -> 8 edge slots
__global__ void k_agg64(const unsigned short* __restrict__ hb, const int* __restrict__ row_ptr,
                        const int* __restrict__ csr_src, const float* __restrict__ dinv,
                        unsigned short* __restrict__ outb) {
    int wv = (blockIdx.x * blockDim.x + threadIdx.x) >> 6;
    int lane = threadIdx.x & 63;
    if (wv >= N_NODES) return;
    int q = lane & 7;           // 16B chunk in row
    int slot = lane >> 3;       // 0..7
    int lo = row_ptr[wv], hi = row_ptr[wv + 1];
    const uint4* hbv = (const uint4*)hb;       // row = 8 x uint4
    float acc[8];
#pragma unroll
    for (int i = 0; i < 8; ++i) acc[i] = 0.f;
    if (slot == 0) {                            // self-loop
        uint4 u = hbv[(size_t)wv * 8 + q];
        acc[0] += blo(u.x); acc[1] += bhi(u.x);
        acc[2] += blo(u.y); acc[3] += bhi(u.y);
        acc[4] += blo(u.z); acc[5] += bhi(u.z);
        acc[6] += blo(u.w); acc[7] += bhi(u.w);
    }
    for (int base = lo; base < hi; base += 32) {
#pragma unroll
        for (int k = 0; k < 4; ++k) {
            int e = base + k * 8 + slot;
            int ee = e < hi ? e : hi - 1;
            int s = csr_src[ee];
            uint4 u = hbv[(size_t)s * 8 + q];
            if (e < hi) {
                acc[0] += blo(u.x); acc[1] += bhi(u.x);
                acc[2] += blo(u.y); acc[3] += bhi(u.y);
                acc[4] += blo(u.z); acc[5] += bhi(u.z);
                acc[6] += blo(u.w); acc[7] += bhi(u.w);
            }
        }
    }
#pragma unroll
    for (int i = 0; i < 8; ++i) {
        acc[i] += __shfl_xor(acc[i], 8);
        acc[i] += __shfl_xor(acc[i], 16);
        acc[i] += __shfl_xor(acc[i], 32);
    }
    if (slot == 0) {
        float din = dinv[wv];
        uint4 w;
        w.x = (unsigned int)f2bf(acc[0] * din) | ((unsigned int)f2bf(acc[1] * din) << 16);
        w.y = (unsigned int)f2bf(acc[2] * din) | ((unsigned int)f2bf(acc[3] * din) << 16);
        w.z = (unsigned int)f2bf(acc[4] * din) | ((unsigned int)f2bf(acc[5] * din) << 16);
        w.w = (unsigned int)f2bf(acc[6] * din) | ((unsigned int)f2bf(acc[7] * din) << 16);
        ((uint4*)outb)[(size_t)wv * 8 + q] = w;
    }
}

// width 128: row = 256 B = 16 chunks x 16 B -> 4 edge slots
__global__ void k_agg128(const unsigned short* __restrict__ hb, const int* __restrict__ row_ptr,
                         const int* __restrict__ csr_src, const float* __restrict__ dinv,
                         unsigned short* __restrict__ outb) {
    int wv = (blockIdx.x * blockDim.x + threadIdx.x) >> 6;
    int lane = threadIdx.x & 63;
    if (wv >= N_NODES) return;
    int q = lane & 15;          // 16B chunk in row
    int slot = lane >> 4;       // 0..3
    int lo = row_ptr[wv], hi = row_ptr[wv + 1];
    const uint4* hbv = (const uint4*)hb;       // row = 16 x uint4
    float acc[8];
#pragma unroll
    for (int i = 0; i < 8; ++i) acc[i] = 0.f;
    if (slot == 0) {                            // self-loop
        uint4 u = hbv[(size_t)wv * 16 + q];
        acc[0] += blo(u.x); acc[1] += bhi(u.x);
        acc[2] += blo(u.y); acc[3] += bhi(u.y);
        acc[4] += blo(u.z); acc[5] += bhi(u.z);
        acc[6] += blo(u.w); acc[7] += bhi(u.w);
    }
    for (int base = lo; base < hi; base += 16) {
#pragma unroll
        for (int k = 0; k < 4; ++k) {
            int e = base + k * 4 + slot;
            int ee = e < hi ? e : hi - 1;
            int s = csr_src[ee];
            uint4 u = hbv[(size_t)s * 16 + q];
            if (e < hi) {
                acc[0] += blo(u.x); acc[1] += bhi(u.x);
                acc[2] += blo(u.y); acc[3] += bhi(u.y);
                acc[4] += blo(u.z); acc[5] += bhi(u.z);
                acc[6] += blo(u.w); acc[7] += bhi(u.w);
            }
        }
    }
#pragma unroll
    for (int i = 0; i < 8; ++i) {
        acc[i] += __shfl_xor(acc[i], 16);
        acc[i] += __shfl_xor(acc[i], 32);
    }
    if (slot == 0) {
        float din = dinv[wv];
        uint4 w;
        w.x = (unsigned int)f2bf(acc[0] * din) | ((unsigned int)f2bf(acc[1] * din) << 16);
        w.y = (unsigned int)f2bf(acc[2] * din) | ((unsigned int)f2bf(acc[3] * din) << 16);
        w.z = (unsigned int)f2bf(acc[4] * din) | ((unsigned int)f2bf(acc[5] * din) << 16);
        w.w = (unsigned int)f2bf(acc[6] * din) | ((unsigned int)f2bf(acc[7] * din) << 16);
        ((uint4*)outb)[(size_t)wv * 16 + q] = w;
    }
}

// ================= MFMA GEMM layer 2: [Nx64]bf16 @ [64x128] + b2 -> hb bf16 ======

__global__ __launch_bounds__(256) void k_gemm_l2_mfma(
    const unsigned short* __restrict__ Ab,   // [N][64] bf16
    const unsigned short* __restrict__ Wb,   // packed [8][128][8] bf16
    const float* __restrict__ b,
    const float* __restrict__ dinv,
    unsigned short* __restrict__ hb) {
    __shared__ float sC[64][128];
    int tid = threadIdx.x;
    int wave = tid >> 6, lane = tid & 63;
    int quad = lane >> 4, l16 = lane & 15;
    int n0 = blockIdx.x * 64;
    int arow = n0 + wave * 16 + l16;
    if (arow >= N_NODES) arow = N_NODES - 1;

    floatx4 acc[8];
#pragma unroll
    for (int t = 0; t < 8; ++t) acc[t] = (floatx4){0.f, 0.f, 0.f, 0.f};

#pragma unroll
    for (int ks = 0; ks < 2; ++ks) {
        short8 a = *(const short8*)(Ab + (size_t)arow * 64 + ks * 32 + quad * 8);
#pragma unroll
        for (int t = 0; t < 8; ++t) {
            short8 bf = *(const short8*)(Wb + (((ks * 4 + quad) * 128) + t * 16 + l16) * 8);
            acc[t] = __builtin_amdgcn_mfma_f32_16x16x32_bf16(a, bf, acc[t], 0, 0, 0);
        }
    }
#pragma unroll
    for (int t = 0; t < 8; ++t)
#pragma unroll
        for (int r = 0; r < 4; ++r)
            sC[wave * 16 + quad * 4 + r][t * 16 + l16] = acc[t][r];
    __syncthreads();
    int tn = tid >> 5, tj = tid & 31;
    float4 bv = *(const float4*)(b + tj * 4);
#pragma unroll
    for (int m = 0; m < 8; ++m) {
        int n = n0 + tn * 8 + m;
        if (n < N_NODES) {
            float di = dinv[n];
            unsigned short h0 = f2bf(fmaxf(sC[tn * 8 + m][tj * 4 + 0] + bv.x, 0.f) * di);
            unsigned short h1 = f2bf(fmaxf(sC[tn * 8 + m][tj * 4 + 1] + bv.y, 0.f) * di);
            unsigned short h2 = f2bf(fmaxf(sC[tn * 8 + m][tj * 4 + 2] + bv.z, 0.f) * di);
            unsigned short h3 = f2bf(fmaxf(sC[tn * 8 + m][tj * 4 + 3] + bv.w, 0.f) * di);
            uint2 w2;
            w2.x = (unsigned int)h0 | ((unsigned int)h1 << 16);
            w2.y = (unsigned int)h2 | ((unsigned int)h3 << 16);
            *(uint2*)(hb + (size_t)n * 128 + tj * 4) = w2;
        }
    }
}

// ======== MFMA GEMM layer 3: [Nx128]bf16 @ [128x128] + b3, relu, fused mean-pool ==

__global__ __launch_bounds__(256) void k_gemm_l3_mfma_pool(
    const unsigned short* __restrict__ Ab,   // [N][128] bf16
    const unsigned short* __restrict__ Wb,   // packed [16][128][8] bf16
    const float* __restrict__ b,
    const int* __restrict__ batch,
    float* __restrict__ pooled) {
    __shared__ float sC[64][128];
    __shared__ float red[8][128];
    __shared__ int sb[64];
    int tid = threadIdx.x;
    int wave = tid >> 6, lane = tid & 63;
    int quad = lane >> 4, l16 = lane & 15;
    int n0 = blockIdx.x * 64;
    int arow = n0 + wave * 16 + l16;
    if (arow >= N_NODES) arow = N_NODES - 1;

    floatx4 acc[8];
#pragma unroll
    for (int t = 0; t < 8; ++t) acc[t] = (floatx4){0.f, 0.f, 0.f, 0.f};

#pragma unroll
    for (int ks = 0; ks < 4; ++ks) {
        short8 a = *(const short8*)(Ab + (size_t)arow * 128 + ks * 32 + quad * 8);
#pragma unroll
        for (int t = 0; t < 8; ++t) {
            short8 bf = *(const short8*)(Wb + (((ks * 4 + quad) * 128) + t * 16 + l16) * 8);
            acc[t] = __builtin_amdgcn_mfma_f32_16x16x32_bf16(a, bf, acc[t], 0, 0, 0);
        }
    }
#pragma unroll
    for (int t = 0; t < 8; ++t) {
        float bc = b[t * 16 + l16];
#pragma unroll
        for (int r = 0; r < 4; ++r)
            sC[wave * 16 + quad * 4 + r][t * 16 + l16] = fmaxf(acc[t][r] + bc, 0.f);
    }
    if (tid < 64) {
        int n = n0 + tid;
        sb[tid] = (n < N_NODES) ? batch[n] : -1;
    }
    __syncthreads();
    int g0 = sb[0];
    int last = (n0 + 63 < N_NODES) ? (n0 + 63) : (N_NODES - 1);
    int g1 = batch[last];
    int tn = tid >> 5, tj = tid & 31;
    for (int g = g0; g <= g1; ++g) {
        float p0 = 0.f, p1 = 0.f, p2 = 0.f, p3 = 0.f;
#pragma unroll
        for (int m = 0; m < 8; ++m) {
            if (sb[tn * 8 + m] == g) {
                p0 += sC[tn * 8 + m][tj * 4 + 0];
                p1 += sC[tn * 8 + m][tj * 4 + 1];
                p2 += sC[tn * 8 + m][tj * 4 + 2];
                p3 += sC[tn * 8 + m][tj * 4 + 3];
            }
        }
        red[tn][tj * 4 + 0] = p0;
        red[tn][tj * 4 + 1] = p1;
        red[tn][tj * 4 + 2] = p2;
        red[tn][tj * 4 + 3] = p3;
        __syncthreads();
        if (tid < 128) {
            float s = 0.f;
#pragma unroll
            for (int r = 0; r < 8; ++r) s += red[r][tid];
            atomicAdd(&pooled[g * 128 + tid], s);
        }
        __syncthreads();
    }
}

// ================= final FC head =================

__device__ __forceinline__ int lower_bound_batch(const int* __restrict__ batch, int val) {
    int lo = 0, hi = N_NODES;
    while (lo < hi) {
        int mid = (lo + hi) >> 1;
        if (batch[mid] < val) lo = mid + 1; else hi = mid;
    }
    return lo;
}

__global__ void k_fc(const float* __restrict__ pooled, const int* __restrict__ batch,
                     const float* __restrict__ Wf1, const float* __restrict__ bf1,
                     const float* __restrict__ Wf2, const float* __restrict__ bf2,
                     float* __restrict__ out) {
    __shared__ float sp[128];
    __shared__ float sh1[64];
    int g = blockIdx.x;
    int t = threadIdx.x;             // 128
    int lo = lower_bound_batch(batch, g);
    int hi = lower_bound_batch(batch, g + 1);
    float inv = 1.0f / fmaxf((float)(hi - lo), 1.0f);
    sp[t] = pooled[g * 128 + t] * inv;
    __syncthreads();
    if (t < 64) {
        float acc = bf1[t];
#pragma unroll 8
        for (int k = 0; k < 128; ++k) acc += sp[k] * Wf1[k * 64 + t];
        sh1[t] = fmaxf(acc, 0.0f);
    }
    __syncthreads();
    if (t < 10) {
        float acc = bf2[t];
#pragma unroll 8
        for (int k = 0; k < 64; ++k) acc += sh1[k] * Wf2[k * 10 + t];
        out[g * 10 + t] = acc;
    }
}

extern "C" void kernel_launch(void* const* d_in, const int* in_sizes, int n_in,
                              void* d_out, int out_size, void* d_ws, size_t ws_size,
                              hipStream_t stream) {
    const float* x     = (const float*)d_in[0];
    const int*   ei    = (const int*)d_in[1];
    const int*   batch = (const int*)d_in[2];
    const float* W1  = (const float*)d_in[3];
    const float* b1  = (const float*)d_in[4];
    const float* W2  = (const float*)d_in[5];
    const float* b2  = (const float*)d_in[6];
    const float* W3  = (const float*)d_in[7];
    const float* b3  = (const float*)d_in[8];
    const float* Wf1 = (const float*)d_in[9];
    const float* bf1 = (const float*)d_in[10];
    const float* Wf2 = (const float*)d_in[11];
    const float* bf2 = (const float*)d_in[12];
    float* out = (float*)d_out;

    const int* src = ei;              // edge_index[0]
    const int* dst = ei + N_EDGES;    // edge_index[1]

    // workspace layout
    float* dinv   = (float*)d_ws;                      // N
    int*   counts = (int*)(dinv + N_NODES);            // N
    int*   row_ptr= counts + N_NODES;                  // N+1
    int*   blksum = row_ptr + N_NODES + 1;             // 256
    int*   cursor = blksum + 256;                      // N
    int*   csr_src= cursor + N_NODES;                  // N_EDGES
    float* xs     = (float*)(csr_src + N_EDGES);       // N*3
    float* a3     = xs + (size_t)N_NODES * 3;          // N*3 (agg3 out)
    unsigned short* Wb2 = (unsigned short*)(a3 + (size_t)N_NODES * 3);  // 8192
    unsigned short* Wb3 = Wb2 + 64 * 128;                               // 16384
    size_t ofs = (size_t)(Wb3 + 128 * 128) - (size_t)d_ws;
    ofs = (ofs + 15) & ~(size_t)15;
    unsigned short* bufA = (unsigned short*)((char*)d_ws + ofs);        // N*128 bf16 (agg out)
    unsigned short* hb   = bufA + (size_t)N_NODES * 128;                // N*128 bf16 (gemm out)
    float* pooled = (float*)(hb + (size_t)N_NODES * 128);               // G*128

    const int TB = 256;
    const int GEMM_BLKS = (N_NODES + 63) / 64;
    const int PREP_N = N_NODES + N_GRAPHS * 128 + 64 * 128 + 128 * 128;

    // ---- prep (zero counts+pooled, cast weights) + CSR build ----
    k_prep<<<(PREP_N + TB - 1) / TB, TB, 0, stream>>>(counts, pooled, W2, W3, Wb2, Wb3);
    k_hist<<<(N_EDGES / 4 + TB - 1) / TB, TB, 0, stream>>>(dst, counts);
    k_scan1<<<SCAN_NBLK, SCAN_B, 0, stream>>>(counts, row_ptr, blksum);
    k_scan3<<<SCAN_NBLK, SCAN_B, 0, stream>>>(row_ptr, blksum, cursor, counts, dinv, x, xs);
    k_fill<<<(N_EDGES / 4 + TB - 1) / TB, TB, 0, stream>>>(src, dst, cursor, csr_src);

    // ---- layer 1: agg3(xs) @ W1 + b1 -> hb = bf16(dinv*relu) ----
    k_agg3<<<(N_NODES + TB - 1) / TB, TB, 0, stream>>>(xs, row_ptr, csr_src, dinv, a3);
    k_node_gemm<3, 64, 4><<<(N_NODES + 3) / 4, 64, 0, stream>>>(a3, W1, b1, dinv, hb);

    // ---- layer 2: agg64(hb) -> bufA bf16; MFMA @ W2 + b2 -> hb bf16 ----
    k_agg64<<<(N_NODES * 64 + TB - 1) / TB, TB, 0, stream>>>(hb, row_ptr, csr_src, dinv, bufA);
    k_gemm_l2_mfma<<<GEMM_BLKS, 256, 0, stream>>>(bufA, Wb2, b2, dinv, hb);

    // ---- layer 3: agg128(hb) -> bufA bf16; MFMA @ W3 + b3, relu, fused pool ----
    k_agg128<<<(N_NODES * 64 + TB - 1) / TB, TB, 0, stream>>>(hb, row_ptr, csr_src, dinv, bufA);
    k_gemm_l3_mfma_pool<<<GEMM_BLKS, 256, 0, stream>>>(bufA, Wb3, b3, batch, pooled);

    // ---- FC head ----
    k_fc<<<N_GRAPHS, 128, 0, stream>>>(pooled, batch, Wf1, bf1, Wf2, bf2, out);
}

// Round 13
// 268.904 us; speedup vs baseline: 1.1399x; 1.1399x over previous
//
#include <hip/hip_runtime.h>

#define N_NODES 50000
#define N_EDGES 800000
#define N_GRAPHS 64
#define SCAN_B 256
#define SCAN_NBLK ((N_NODES + SCAN_B - 1) / SCAN_B)   // 196 buckets of 256 nodes
#define FILL_E 2048

typedef __attribute__((ext_vector_type(8))) short short8;
typedef __attribute__((ext_vector_type(4))) float floatx4;

// fp32 -> bf16 round-to-nearest-even
__device__ __forceinline__ unsigned short f2bf(float f) {
    unsigned int u = __float_as_uint(f);
    u += 0x7FFFu + ((u >> 16) & 1u);
    return (unsigned short)(u >> 16);
}
__device__ __forceinline__ float bf2f(unsigned short h) {
    return __uint_as_float(((unsigned int)h) << 16);
}
__device__ __forceinline__ float blo(unsigned int u) { return __uint_as_float(u << 16); }
__device__ __forceinline__ float bhi(unsigned int u) { return __uint_as_float(u & 0xffff0000u); }

// ========== prep: zero counts + pooled, cast W2/W3 to packed bf16 B-frag layout ====

__global__ void k_prep(int* counts, float* pooled,
                       const float* __restrict__ W2, const float* __restrict__ W3,
                       unsigned short* Wb2, unsigned short* Wb3) {
    int i = blockIdx.x * blockDim.x + threadIdx.x;
    if (i < N_NODES) counts[i] = 0;
    int j = i - N_NODES;
    if (j >= 0 && j < N_GRAPHS * 128) pooled[j] = 0.0f;
    int k = i - N_NODES - N_GRAPHS * 128;
    if (k >= 0 && k < 64 * 128) {
        int kk = k >> 7, n = k & 127;
        Wb2[(((kk >> 3) * 128) + n) * 8 + (kk & 7)] = f2bf(W2[k]);
    }
    int l = i - N_NODES - N_GRAPHS * 128 - 64 * 128;
    if (l >= 0 && l < 128 * 128) {
        int kk = l >> 7, n = l & 127;
        Wb3[(((kk >> 3) * 128) + n) * 8 + (kk & 7)] = f2bf(W3[l]);
    }
}

// ================= CSR build =================

__global__ void k_hist(const int* __restrict__ dst, int* counts) {
    int i = blockIdx.x * blockDim.x + threadIdx.x;
    if (i < N_EDGES) atomicAdd(&counts[dst[i]], 1);
}

__global__ void k_scan1(const int* __restrict__ counts, int* row_ptr, int* blksum) {
    __shared__ int s[SCAN_B];
    int i = blockIdx.x * SCAN_B + threadIdx.x;
    int c = (i < N_NODES) ? counts[i] : 0;
    s[threadIdx.x] = c;
    __syncthreads();
    for (int off = 1; off < SCAN_B; off <<= 1) {
        int v = (threadIdx.x >= off) ? s[threadIdx.x - off] : 0;
        __syncthreads();
        s[threadIdx.x] += v;
        __syncthreads();
    }
    if (i < N_NODES) row_ptr[i] = s[threadIdx.x] - c;   // exclusive within block
    if (threadIdx.x == SCAN_B - 1) blksum[blockIdx.x] = s[SCAN_B - 1];  // raw block sum
}

// finalize row_ptr (block offset via in-LDS reduction of prior raw block sums),
// init bucket cursor, dinv = rsqrt(deg), xs = x * dinv.  One block == one bucket.
__global__ void k_scan3(int* row_ptr, const int* __restrict__ blksum,
                        int* bcursor, const int* __restrict__ counts, float* dinv,
                        const float* __restrict__ x, float* __restrict__ xs) {
    __shared__ int s[SCAN_B];
    int t = threadIdx.x;
    int b = blockIdx.x;
    s[t] = (t < b && t < SCAN_NBLK) ? blksum[t] : 0;
    __syncthreads();
    for (int off = SCAN_B / 2; off > 0; off >>= 1) {
        if (t < off) s[t] += s[t + off];
        __syncthreads();
    }
    int offset = s[0];
    if (t == 0) bcursor[b] = offset;           // bucket b's CSR start
    int i = b * SCAN_B + t;
    if (i < N_NODES) {
        row_ptr[i] += offset;
        float di = rsqrtf((float)(counts[i] + 1));
        dinv[i] = di;
        xs[i * 3 + 0] = x[i * 3 + 0] * di;
        xs[i * 3 + 1] = x[i * 3 + 1] * di;
        xs[i * 3 + 2] = x[i * 3 + 2] * di;
    }
    if (i == 0) row_ptr[N_NODES] = N_EDGES;
}

// pass B: LDS counting-sort 2048 edges by bucket (dst>>8), flush contiguous runs
__global__ __launch_bounds__(256) void k_binfill(const int* __restrict__ src,
                                                 const int* __restrict__ dst,
                                                 int* bcursor, int2* __restrict__ bpair) {
    __shared__ int cnt[SCAN_B];
    __shared__ int sc[SCAN_B];
    __shared__ int base[SCAN_B];
    __shared__ int delta[SCAN_B];
    __shared__ int ofs[SCAN_B];
    __shared__ int2 stage[FILL_E];             // 16 KB
    __shared__ unsigned char bk[FILL_E];       // 2 KB
    int tid = threadIdx.x;
    int e0 = blockIdx.x * FILL_E + tid * 8;
    cnt[tid] = 0; ofs[tid] = 0;
    __syncthreads();
    int s[8], d[8], bb[8];
    bool active = e0 < N_EDGES;                // tails are multiples of 8
    if (active) {
        int4 sa = *(const int4*)(src + e0);
        int4 sb = *(const int4*)(src + e0 + 4);
        int4 da = *(const int4*)(dst + e0);
        int4 db = *(const int4*)(dst + e0 + 4);
        s[0]=sa.x; s[1]=sa.y; s[2]=sa.z; s[3]=sa.w;
        s[4]=sb.x; s[5]=sb.y; s[6]=sb.z; s[7]=sb.w;
        d[0]=da.x; d[1]=da.y; d[2]=da.z; d[3]=da.w;
        d[4]=db.x; d[5]=db.y; d[6]=db.z; d[7]=db.w;
#pragma unroll
        for (int k = 0; k < 8; ++k) {
            bb[k] = d[k] >> 8;
            atomicAdd(&cnt[bb[k]], 1);
        }
    }
    __syncthreads();
    int c = cnt[tid];
    sc[tid] = c;
    __syncthreads();
    for (int off = 1; off < SCAN_B; off <<= 1) {
        int v = (tid >= off) ? sc[tid - off] : 0;
        __syncthreads();
        sc[tid] += v;
        __syncthreads();
    }
    base[tid] = sc[tid] - c;                   // exclusive scan
    if (c > 0) delta[tid] = atomicAdd(&bcursor[tid], c) - base[tid];
    __syncthreads();
    if (active) {
#pragma unroll
        for (int k = 0; k < 8; ++k) {
            int p = base[bb[k]] + atomicAdd(&ofs[bb[k]], 1);
            stage[p] = make_int2(s[k], d[k]);
            bk[p] = (unsigned char)bb[k];
        }
    }
    __syncthreads();
    int total = base[SCAN_B - 1] + cnt[SCAN_B - 1];
    for (int i = tid; i < total; i += 256)
        bpair[delta[bk[i]] + i] = stage[i];
}

// pass C: one block per bucket; scatter src into the bucket's dense CSR window
__global__ __launch_bounds__(256) void k_fill2(const int2* __restrict__ bpair,
                                               const int* __restrict__ row_ptr,
                                               int* __restrict__ csr_src) {
    __shared__ int cur[SCAN_B];
    int b = blockIdx.x;
    int t = threadIdx.x;
    int n0 = b * SCAN_B;
    int n = n0 + t;
    cur[t] = (n < N_NODES) ? row_ptr[n] : 0;
    int start = row_ptr[n0];
    int endn = (n0 + SCAN_B < N_NODES) ? (n0 + SCAN_B) : N_NODES;
    int end = row_ptr[endn];
    __syncthreads();
    for (int i = start + t; i < end; i += 256) {
        int2 pr = bpair[i];
        int pos = atomicAdd(&cur[pr.y & (SCAN_B - 1)], 1);
        csr_src[pos] = pr.x;
    }
}

// ================= layer 1: agg width 3 + small GEMM ==================

__global__ void k_agg3(const float* __restrict__ xs, const int* __restrict__ row_ptr,
                       const int* __restrict__ csr_src, const float* __restrict__ dinv,
                       float* __restrict__ out) {
    int n = blockIdx.x * blockDim.x + threadIdx.x;
    if (n >= N_NODES) return;
    int lo = row_ptr[n], hi = row_ptr[n + 1];
    float a0 = xs[n * 3 + 0], a1 = xs[n * 3 + 1], a2 = xs[n * 3 + 2];
    for (int i = lo; i < hi; ++i) {
        int s = csr_src[i];
        a0 += xs[s * 3 + 0];
        a1 += xs[s * 3 + 1];
        a2 += xs[s * 3 + 2];
    }
    float din = dinv[n];
    out[n * 3 + 0] = a0 * din;
    out[n * 3 + 1] = a1 * din;
    out[n * 3 + 2] = a2 * din;
}

template<int IN_W, int OUT_W, int NPB>
__global__ void k_node_gemm(const float* __restrict__ h, const float* __restrict__ W,
                            const float* __restrict__ b, const float* __restrict__ dinv,
                            unsigned short* __restrict__ hb) {
    __shared__ float rows[NPB][IN_W];
    int n0 = blockIdx.x * NPB;
    int j = threadIdx.x;                         // blockDim.x == OUT_W
    for (int t = j; t < NPB * IN_W; t += OUT_W) {
        int m = t / IN_W, k = t - m * IN_W;
        int n = n0 + m;
        rows[m][k] = (n < N_NODES) ? h[(size_t)n * IN_W + k] : 0.0f;
    }
    __syncthreads();
    float acc[NPB];
    float bj = b[j];
#pragma unroll
    for (int m = 0; m < NPB; ++m) acc[m] = bj;
#pragma unroll
    for (int k = 0; k < IN_W; ++k) {
        float wk = W[k * OUT_W + j];
#pragma unroll
        for (int m = 0; m < NPB; ++m) acc[m] += rows[m][k] * wk;
    }
#pragma unroll
    for (int m = 0; m < NPB; ++m) {
        int n = n0 + m;
        if (n < N_NODES)
            hb[(size_t)n * OUT_W + j] = f2bf(fmaxf(acc[m], 0.0f) * dinv[n]);
    }
}

// ================= aggregation (wave per node, multi-row dwordx4 gathers) =========

// width 64: row = 128 B = 8 chunks x 16 B -> 8 edge slots
__global__ void k_agg64(const unsigned short* __restrict__ hb, const int* __restrict__ row_ptr,
                        const int* __restrict__ csr_src, const float* __restrict__ dinv,
                        unsigned short* __restrict__ outb) {
    int wv = (blockIdx.x * blockDim.x + threadIdx.x) >> 6;
    int lane = threadIdx.x & 63;
    if (wv >= N_NODES) return;
    int q = lane & 7;           // 16B chunk in row
    int slot = lane >> 3;       // 0..7
    int lo = row_ptr[wv], hi = row_ptr[wv + 1];
    const uint4* hbv = (const uint4*)hb;       // row = 8 x uint4
    float acc[8];
#pragma unroll
    for (int i = 0; i < 8; ++i) acc[i] = 0.f;
    if (slot == 0) {                            // self-loop
        uint4 u = hbv[(size_t)wv * 8 + q];
        acc[0] += blo(u.x); acc[1] += bhi(u.x);
        acc[2] += blo(u.y); acc[3] += bhi(u.y);
        acc[4] += blo(u.z); acc[5] += bhi(u.z);
        acc[6] += blo(u.w); acc[7] += bhi(u.w);
    }
    for (int base = lo; base < hi; base += 32) {
#pragma unroll
        for (int k = 0; k < 4; ++k) {
            int e = base + k * 8 + slot;
            int ee = e < hi ? e : hi - 1;
            int s = csr_src[ee];
            uint4 u = hbv[(size_t)s * 8 + q];
            if (e < hi) {
                acc[0] += blo(u.x); acc[1] += bhi(u.x);
                acc[2] += blo(u.y); acc[3] += bhi(u.y);
                acc[4] += blo(u.z); acc[5] += bhi(u.z);
                acc[6] += blo(u.w); acc[7] += bhi(u.w);
            }
        }
    }
#pragma unroll
    for (int i = 0; i < 8; ++i) {
        acc[i] += __shfl_xor(acc[i], 8);
        acc[i] += __shfl_xor(acc[i], 16);
        acc[i] += __shfl_xor(acc[i], 32);
    }
    if (slot == 0) {
        float din = dinv[wv];
        uint4 w;
        w.x = (unsigned int)f2bf(acc[0] * din) | ((unsigned int)f2bf(acc[1] * din) << 16);
        w.y = (unsigned int)f2bf(acc[2] * din) | ((unsigned int)f2bf(acc[3] * din) << 16);
        w.z = (unsigned int)f2bf(acc[4] * din) | ((unsigned int)f2bf(acc[5] * din) << 16);
        w.w = (unsigned int)f2bf(acc[6] * din) | ((unsigned int)f2bf(acc[7] * din) << 16);
        ((uint4*)outb)[(size_t)wv * 8 + q] = w;
    }
}

// width 128: row = 256 B = 16 chunks x 16 B -> 4 edge slots
__global__ void k_agg128(const unsigned short* __restrict__ hb, const int* __restrict__ row_ptr,
                         const int* __restrict__ csr_src, const float* __restrict__ dinv,
                         unsigned short* __restrict__ outb) {
    int wv = (blockIdx.x * blockDim.x + threadIdx.x) >> 6;
    int lane = threadIdx.x & 63;
    if (wv >= N_NODES) return;
    int q = lane & 15;          // 16B chunk in row
    int slot = lane >> 4;       // 0..3
    int lo = row_ptr[wv], hi = row_ptr[wv + 1];
    const uint4* hbv = (const uint4*)hb;       // row = 16 x uint4
    float acc[8];
#pragma unroll
    for (int i = 0; i < 8; ++i) acc[i] = 0.f;
    if (slot == 0) {                            // self-loop
        uint4 u = hbv[(size_t)wv * 16 + q];
        acc[0] += blo(u.x); acc[1] += bhi(u.x);
        acc[2] += blo(u.y); acc[3] += bhi(u.y);
        acc[4] += blo(u.z); acc[5] += bhi(u.z);
        acc[6] += blo(u.w); acc[7] += bhi(u.w);
    }
    for (int base = lo; base < hi; base += 16) {
#pragma unroll
        for (int k = 0; k < 4; ++k) {
            int e = base + k * 4 + slot;
            int ee = e < hi ? e : hi - 1;
            int s = csr_src[ee];
            uint4 u = hbv[(size_t)s * 16 + q];
            if (e < hi) {
                acc[0] += blo(u.x); acc[1] += bhi(u.x);
                acc[2] += blo(u.y); acc[3] += bhi(u.y);
                acc[4] += blo(u.z); acc[5] += bhi(u.z);
                acc[6] += blo(u.w); acc[7] += bhi(u.w);
            }
        }
    }
#pragma unroll
    for (int i = 0; i < 8; ++i) {
        acc[i] += __shfl_xor(acc[i], 16);
        acc[i] += __shfl_xor(acc[i], 32);
    }
    if (slot == 0) {
        float din = dinv[wv];
        uint4 w;
        w.x = (unsigned int)f2bf(acc[0] * din) | ((unsigned int)f2bf(acc[1] * din) << 16);
        w.y = (unsigned int)f2bf(acc[2] * din) | ((unsigned int)f2bf(acc[3] * din) << 16);
        w.z = (unsigned int)f2bf(acc[4] * din) | ((unsigned int)f2bf(acc[5] * din) << 16);
        w.w = (unsigned int)f2bf(acc[6] * din) | ((unsigned int)f2bf(acc[7] * din) << 16);
        ((uint4*)outb)[(size_t)wv * 16 + q] = w;
    }
}

// ================= MFMA GEMM layer 2: [Nx64]bf16 @ [64x128] + b2 -> hb bf16 ======

__global__ __launch_bounds__(256) void k_gemm_l2_mfma(
    const unsigned short* __restrict__ Ab,   // [N][64] bf16
    const unsigned short* __restrict__ Wb,   // packed [8][128][8] bf16
    const float* __restrict__ b,
    const float* __restrict__ dinv,
    unsigned short* __restrict__ hb) {
    __shared__ float sC[64][128];
    int tid = threadIdx.x;
    int wave = tid >> 6, lane = tid & 63;
    int quad = lane >> 4, l16 = lane & 15;
    int n0 = blockIdx.x * 64;
    int arow = n0 + wave * 16 + l16;
    if (arow >= N_NODES) arow = N_NODES - 1;

    floatx4 acc[8];
#pragma unroll
    for (int t = 0; t < 8; ++t) acc[t] = (floatx4){0.f, 0.f, 0.f, 0.f};

#pragma unroll
    for (int ks = 0; ks < 2; ++ks) {
        short8 a = *(const short8*)(Ab + (size_t)arow * 64 + ks * 32 + quad * 8);
#pragma unroll
        for (int t = 0; t < 8; ++t) {
            short8 bf = *(const short8*)(Wb + (((ks * 4 + quad) * 128) + t * 16 + l16) * 8);
            acc[t] = __builtin_amdgcn_mfma_f32_16x16x32_bf16(a, bf, acc[t], 0, 0, 0);
        }
    }
#pragma unroll
    for (int t = 0; t < 8; ++t)
#pragma unroll
        for (int r = 0; r < 4; ++r)
            sC[wave * 16 + quad * 4 + r][t * 16 + l16] = acc[t][r];
    __syncthreads();
    int tn = tid >> 5, tj = tid & 31;
    float4 bv = *(const float4*)(b + tj * 4);
#pragma unroll
    for (int m = 0; m < 8; ++m) {
        int n = n0 + tn * 8 + m;
        if (n < N_NODES) {
            float di = dinv[n];
            unsigned short h0 = f2bf(fmaxf(sC[tn * 8 + m][tj * 4 + 0] + bv.x, 0.f) * di);
            unsigned short h1 = f2bf(fmaxf(sC[tn * 8 + m][tj * 4 + 1] + bv.y, 0.f) * di);
            unsigned short h2 = f2bf(fmaxf(sC[tn * 8 + m][tj * 4 + 2] + bv.z, 0.f) * di);
            unsigned short h3 = f2bf(fmaxf(sC[tn * 8 + m][tj * 4 + 3] + bv.w, 0.f) * di);
            uint2 w2;
            w2.x = (unsigned int)h0 | ((unsigned int)h1 << 16);
            w2.y = (unsigned int)h2 | ((unsigned int)h3 << 16);
            *(uint2*)(hb + (size_t)n * 128 + tj * 4) = w2;
        }
    }
}

// ======== MFMA GEMM layer 3: [Nx128]bf16 @ [128x128] + b3, relu, fused mean-pool ==

__global__ __launch_bounds__(256) void k_gemm_l3_mfma_pool(
    const unsigned short* __restrict__ Ab,   // [N][128] bf16
    const unsigned short* __restrict__ Wb,   // packed [16][128][8] bf16
    const float* __restrict__ b,
    const int* __restrict__ batch,
    float* __restrict__ pooled) {
    __shared__ float sC[64][128];
    __shared__ float red[8][128];
    __shared__ int sb[64];
    int tid = threadIdx.x;
    int wave = tid >> 6, lane = tid & 63;
    int quad = lane >> 4, l16 = lane & 15;
    int n0 = blockIdx.x * 64;
    int arow = n0 + wave * 16 + l16;
    if (arow >= N_NODES) arow = N_NODES - 1;

    floatx4 acc[8];
#pragma unroll
    for (int t = 0; t < 8; ++t) acc[t] = (floatx4){0.f, 0.f, 0.f, 0.f};

#pragma unroll
    for (int ks = 0; ks < 4; ++ks) {
        short8 a = *(const short8*)(Ab + (size_t)arow * 128 + ks * 32 + quad * 8);
#pragma unroll
        for (int t = 0; t < 8; ++t) {
            short8 bf = *(const short8*)(Wb + (((ks * 4 + quad) * 128) + t * 16 + l16) * 8);
            acc[t] = __builtin_amdgcn_mfma_f32_16x16x32_bf16(a, bf, acc[t], 0, 0, 0);
        }
    }
#pragma unroll
    for (int t = 0; t < 8; ++t) {
        float bc = b[t * 16 + l16];
#pragma unroll
        for (int r = 0; r < 4; ++r)
            sC[wave * 16 + quad * 4 + r][t * 16 + l16] = fmaxf(acc[t][r] + bc, 0.f);
    }
    if (tid < 64) {
        int n = n0 + tid;
        sb[tid] = (n < N_NODES) ? batch[n] : -1;
    }
    __syncthreads();
    int g0 = sb[0];
    int last = (n0 + 63 < N_NODES) ? (n0 + 63) : (N_NODES - 1);
    int g1 = batch[last];
    int tn = tid >> 5, tj = tid & 31;
    for (int g = g0; g <= g1; ++g) {
        float p0 = 0.f, p1 = 0.f, p2 = 0.f, p3 = 0.f;
#pragma unroll
        for (int m = 0; m < 8; ++m) {
            if (sb[tn * 8 + m] == g) {
                p0 += sC[tn * 8 + m][tj * 4 + 0];
                p1 += sC[tn * 8 + m][tj * 4 + 1];
                p2 += sC[tn * 8 + m][tj * 4 + 2];
                p3 += sC[tn * 8 + m][tj * 4 + 3];
            }
        }
        red[tn][tj * 4 + 0] = p0;
        red[tn][tj * 4 + 1] = p1;
        red[tn][tj * 4 + 2] = p2;
        red[tn][tj * 4 + 3] = p3;
        __syncthreads();
        if (tid < 128) {
            float s = 0.f;
#pragma unroll
            for (int r = 0; r < 8; ++r) s += red[r][tid];
            atomicAdd(&pooled[g * 128 + tid], s);
        }
        __syncthreads();
    }
}

// ================= final FC head =================

__device__ __forceinline__ int lower_bound_batch(const int* __restrict__ batch, int val) {
    int lo = 0, hi = N_NODES;
    while (lo < hi) {
        int mid = (lo + hi) >> 1;
        if (batch[mid] < val) lo = mid + 1; else hi = mid;
    }
    return lo;
}

__global__ void k_fc(const float* __restrict__ pooled, const int* __restrict__ batch,
                     const float* __restrict__ Wf1, const float* __restrict__ bf1,
                     const float* __restrict__ Wf2, const float* __restrict__ bf2,
                     float* __restrict__ out) {
    __shared__ float sp[128];
    __shared__ float sh1[64];
    int g = blockIdx.x;
    int t = threadIdx.x;             // 128
    int lo = lower_bound_batch(batch, g);
    int hi = lower_bound_batch(batch, g + 1);
    float inv = 1.0f / fmaxf((float)(hi - lo), 1.0f);
    sp[t] = pooled[g * 128 + t] * inv;
    __syncthreads();
    if (t < 64) {
        float acc = bf1[t];
#pragma unroll 8
        for (int k = 0; k < 128; ++k) acc += sp[k] * Wf1[k * 64 + t];
        sh1[t] = fmaxf(acc, 0.0f);
    }
    __syncthreads();
    if (t < 10) {
        float acc = bf2[t];
#pragma unroll 8
        for (int k = 0; k < 64; ++k) acc += sh1[k] * Wf2[k * 10 + t];
        out[g * 10 + t] = acc;
    }
}

extern "C" void kernel_launch(void* const* d_in, const int* in_sizes, int n_in,
                              void* d_out, int out_size, void* d_ws, size_t ws_size,
                              hipStream_t stream) {
    const float* x     = (const float*)d_in[0];
    const int*   ei    = (const int*)d_in[1];
    const int*   batch = (const int*)d_in[2];
    const float* W1  = (const float*)d_in[3];
    const float* b1  = (const float*)d_in[4];
    const float* W2  = (const float*)d_in[5];
    const float* b2  = (const float*)d_in[6];
    const float* W3  = (const float*)d_in[7];
    const float* b3  = (const float*)d_in[8];
    const float* Wf1 = (const float*)d_in[9];
    const float* bf1 = (const float*)d_in[10];
    const float* Wf2 = (const float*)d_in[11];
    const float* bf2 = (const float*)d_in[12];
    float* out = (float*)d_out;

    const int* src = ei;              // edge_index[0]
    const int* dst = ei + N_EDGES;    // edge_index[1]

    // workspace layout
    float* dinv   = (float*)d_ws;                      // N
    int*   counts = (int*)(dinv + N_NODES);            // N
    int*   row_ptr= counts + N_NODES;                  // N+1
    int*   blksum = row_ptr + N_NODES + 1;             // 256
    int*   bcursor= blksum + 256;                      // 256
    int*   csr_src= bcursor + 256;                     // N_EDGES
    int2*  bpair  = (int2*)(csr_src + N_EDGES);        // N_EDGES int2 (8B aligned)
    float* xs     = (float*)(bpair + N_EDGES);         // N*3
    float* a3     = xs + (size_t)N_NODES * 3;          // N*3 (agg3 out)
    unsigned short* Wb2 = (unsigned short*)(a3 + (size_t)N_NODES * 3);  // 8192
    unsigned short* Wb3 = Wb2 + 64 * 128;                               // 16384
    size_t ofs = (size_t)(Wb3 + 128 * 128) - (size_t)d_ws;
    ofs = (ofs + 15) & ~(size_t)15;
    unsigned short* bufA = (unsigned short*)((char*)d_ws + ofs);        // N*128 bf16 (agg out)
    unsigned short* hb   = bufA + (size_t)N_NODES * 128;                // N*128 bf16 (gemm out)
    float* pooled = (float*)(hb + (size_t)N_NODES * 128);               // G*128

    const int TB = 256;
    const int GEMM_BLKS = (N_NODES + 63) / 64;
    const int PREP_N = N_NODES + N_GRAPHS * 128 + 64 * 128 + 128 * 128;
    const int BIN_BLKS = (N_EDGES + FILL_E - 1) / FILL_E;

    // ---- prep (zero counts+pooled, cast weights) + CSR build ----
    k_prep<<<(PREP_N + TB - 1) / TB, TB, 0, stream>>>(counts, pooled, W2, W3, Wb2, Wb3);
    k_hist<<<(N_EDGES + TB - 1) / TB, TB, 0, stream>>>(dst, counts);
    k_scan1<<<SCAN_NBLK, SCAN_B, 0, stream>>>(counts, row_ptr, blksum);
    k_scan3<<<SCAN_NBLK, SCAN_B, 0, stream>>>(row_ptr, blksum, bcursor, counts, dinv, x, xs);
    k_binfill<<<BIN_BLKS, 256, 0, stream>>>(src, dst, bcursor, bpair);
    k_fill2<<<SCAN_NBLK, 256, 0, stream>>>(bpair, row_ptr, csr_src);

    // ---- layer 1: agg3(xs) @ W1 + b1 -> hb = bf16(dinv*relu) ----
    k_agg3<<<(N_NODES + TB - 1) / TB, TB, 0, stream>>>(xs, row_ptr, csr_src, dinv, a3);
    k_node_gemm<3, 64, 4><<<(N_NODES + 3) / 4, 64, 0, stream>>>(a3, W1, b1, dinv, hb);

    // ---- layer 2: agg64(hb) -> bufA bf16; MFMA @ W2 + b2 -> hb bf16 ----
    k_agg64<<<(N_NODES * 64 + TB - 1) / TB, TB, 0, stream>>>(hb, row_ptr, csr_src, dinv, bufA);
    k_gemm_l2_mfma<<<GEMM_BLKS, 256, 0, stream>>>(bufA, Wb2, b2, dinv, hb);

    // ---- layer 3: agg128(hb) -> bufA bf16; MFMA @ W3 + b3, relu, fused pool ----
    k_agg128<<<(N_NODES * 64 + TB - 1) / TB, TB, 0, stream>>>(hb, row_ptr, csr_src, dinv, bufA);
    k_gemm_l3_mfma_pool<<<GEMM_BLKS, 256, 0, stream>>>(bufA, Wb3, b3, batch, pooled);

    // ---- FC head ----
    k_fc<<<N_GRAPHS, 128, 0, stream>>>(pooled, batch, Wf1, bf1, Wf2, bf2, out);
}

// Round 14
// 238.522 us; speedup vs baseline: 1.2851x; 1.1274x over previous
//
#include <hip/hip_runtime.h>

#define N_NODES 50000
#define N_EDGES 800000
#define N_GRAPHS 64
#define SCAN_B 256
#define SCAN_NBLK ((N_NODES + SCAN_B - 1) / SCAN_B)   // 196 buckets of 256 nodes
#define FILL_E 2048

typedef __attribute__((ext_vector_type(8))) short short8;
typedef __attribute__((ext_vector_type(4))) float floatx4;

// fp32 -> bf16 round-to-nearest-even
__device__ __forceinline__ unsigned short f2bf(float f) {
    unsigned int u = __float_as_uint(f);
    u += 0x7FFFu + ((u >> 16) & 1u);
    return (unsigned short)(u >> 16);
}
__device__ __forceinline__ float bf2f(unsigned short h) {
    return __uint_as_float(((unsigned int)h) << 16);
}
__device__ __forceinline__ float blo(unsigned int u) { return __uint_as_float(u << 16); }
__device__ __forceinline__ float bhi(unsigned int u) { return __uint_as_float(u & 0xffff0000u); }

// ========== prep: zero bcnt + pooled, cast W2/W3 to packed bf16 B-frag layout ====

__global__ void k_prep(int* bcnt, float* pooled,
                       const float* __restrict__ W2, const float* __restrict__ W3,
                       unsigned short* Wb2, unsigned short* Wb3) {
    int i = blockIdx.x * blockDim.x + threadIdx.x;
    if (i < 256) bcnt[i] = 0;
    int j = i - 256;
    if (j >= 0 && j < N_GRAPHS * 128) pooled[j] = 0.0f;
    int k = i - 256 - N_GRAPHS * 128;
    if (k >= 0 && k < 64 * 128) {
        int kk = k >> 7, n = k & 127;
        Wb2[(((kk >> 3) * 128) + n) * 8 + (kk & 7)] = f2bf(W2[k]);
    }
    int l = i - 256 - N_GRAPHS * 128 - 64 * 128;
    if (l >= 0 && l < 128 * 128) {
        int kk = l >> 7, n = l & 127;
        Wb3[(((kk >> 3) * 128) + n) * 8 + (kk & 7)] = f2bf(W3[l]);
    }
}

// ================= CSR build (bucketed, no node-grain global atomics) ============

// per-bucket edge counts, LDS-aggregated
__global__ __launch_bounds__(256) void k_bhist(const int* __restrict__ dst, int* bcnt) {
    __shared__ int bins[SCAN_NBLK];
    int t = threadIdx.x;
    for (int i = t; i < SCAN_NBLK; i += 256) bins[i] = 0;
    __syncthreads();
    int stride = gridDim.x * blockDim.x;
    for (int i4 = blockIdx.x * blockDim.x + t; i4 < N_EDGES / 4; i4 += stride) {
        int4 d = ((const int4*)dst)[i4];
        atomicAdd(&bins[d.x >> 8], 1);
        atomicAdd(&bins[d.y >> 8], 1);
        atomicAdd(&bins[d.z >> 8], 1);
        atomicAdd(&bins[d.w >> 8], 1);
    }
    __syncthreads();
    for (int i = t; i < SCAN_NBLK; i += 256)
        if (bins[i]) atomicAdd(&bcnt[i], bins[i]);
}

// single block: exclusive scan of bucket counts -> bstart (197 entries), bcursor
__global__ __launch_bounds__(256) void k_bscan(const int* __restrict__ bcnt,
                                               int* bstart, int* bcursor) {
    __shared__ int s[256];
    int t = threadIdx.x;
    int c = (t < SCAN_NBLK) ? bcnt[t] : 0;
    s[t] = c;
    __syncthreads();
    for (int off = 1; off < 256; off <<= 1) {
        int v = (t >= off) ? s[t - off] : 0;
        __syncthreads();
        s[t] += v;
        __syncthreads();
    }
    int excl = s[t] - c;
    bstart[t] = excl;                 // t >= SCAN_NBLK gets total = N_EDGES
    bcursor[t] = excl;
    if (t == 255) bstart[256] = s[255];
}

// LDS counting-sort 2048 edges by bucket (dst>>8), flush contiguous runs
__global__ __launch_bounds__(256) void k_binfill(const int* __restrict__ src,
                                                 const int* __restrict__ dst,
                                                 int* bcursor, int2* __restrict__ bpair) {
    __shared__ int cnt[SCAN_B];
    __shared__ int sc[SCAN_B];
    __shared__ int base[SCAN_B];
    __shared__ int delta[SCAN_B];
    __shared__ int ofs[SCAN_B];
    __shared__ int2 stage[FILL_E];             // 16 KB
    __shared__ unsigned char bk[FILL_E];       // 2 KB
    int tid = threadIdx.x;
    int e0 = blockIdx.x * FILL_E + tid * 8;
    cnt[tid] = 0; ofs[tid] = 0;
    __syncthreads();
    int s[8], d[8], bb[8];
    bool active = e0 < N_EDGES;                // tails are multiples of 8
    if (active) {
        int4 sa = *(const int4*)(src + e0);
        int4 sb = *(const int4*)(src + e0 + 4);
        int4 da = *(const int4*)(dst + e0);
        int4 db = *(const int4*)(dst + e0 + 4);
        s[0]=sa.x; s[1]=sa.y; s[2]=sa.z; s[3]=sa.w;
        s[4]=sb.x; s[5]=sb.y; s[6]=sb.z; s[7]=sb.w;
        d[0]=da.x; d[1]=da.y; d[2]=da.z; d[3]=da.w;
        d[4]=db.x; d[5]=db.y; d[6]=db.z; d[7]=db.w;
#pragma unroll
        for (int k = 0; k < 8; ++k) {
            bb[k] = d[k] >> 8;
            atomicAdd(&cnt[bb[k]], 1);
        }
    }
    __syncthreads();
    int c = cnt[tid];
    sc[tid] = c;
    __syncthreads();
    for (int off = 1; off < SCAN_B; off <<= 1) {
        int v = (tid >= off) ? sc[tid - off] : 0;
        __syncthreads();
        sc[tid] += v;
        __syncthreads();
    }
    base[tid] = sc[tid] - c;                   // exclusive scan
    if (c > 0) delta[tid] = atomicAdd(&bcursor[tid], c) - base[tid];
    __syncthreads();
    if (active) {
#pragma unroll
        for (int k = 0; k < 8; ++k) {
            int p = base[bb[k]] + atomicAdd(&ofs[bb[k]], 1);
            stage[p] = make_int2(s[k], d[k]);
            bk[p] = (unsigned char)bb[k];
        }
    }
    __syncthreads();
    int total = base[SCAN_B - 1] + cnt[SCAN_B - 1];
    for (int i = tid; i < total; i += 256)
        bpair[delta[bk[i]] + i] = stage[i];
}

// one block per bucket: LDS node-histogram -> LDS scan -> row_ptr/dinv/xs -> scatter
__global__ __launch_bounds__(256) void k_build(const int2* __restrict__ bpair,
                                               const int* __restrict__ bstart,
                                               int* row_ptr, int* __restrict__ csr_src,
                                               float* dinv,
                                               const float* __restrict__ x,
                                               float* __restrict__ xs) {
    __shared__ int cnt[SCAN_B];
    __shared__ int sc[SCAN_B];
    __shared__ int cur[SCAN_B];
    int b = blockIdx.x, t = threadIdx.x;
    int start = bstart[b], end = bstart[b + 1];
    cnt[t] = 0;
    __syncthreads();
    for (int i = start + t; i < end; i += 256)
        atomicAdd(&cnt[bpair[i].y & (SCAN_B - 1)], 1);
    __syncthreads();
    int c = cnt[t];
    sc[t] = c;
    __syncthreads();
    for (int off = 1; off < SCAN_B; off <<= 1) {
        int v = (t >= off) ? sc[t - off] : 0;
        __syncthreads();
        sc[t] += v;
        __syncthreads();
    }
    int pos = start + sc[t] - c;               // node's CSR start
    cur[t] = pos;
    int n = b * SCAN_B + t;
    if (n < N_NODES) {
        row_ptr[n] = pos;
        float di = rsqrtf((float)(c + 1));
        dinv[n] = di;
        xs[n * 3 + 0] = x[n * 3 + 0] * di;
        xs[n * 3 + 1] = x[n * 3 + 1] * di;
        xs[n * 3 + 2] = x[n * 3 + 2] * di;
    }
    if (n == N_NODES) row_ptr[N_NODES] = N_EDGES;
    __syncthreads();
    for (int i = start + t; i < end; i += 256) {
        int2 pr = bpair[i];
        int p = atomicAdd(&cur[pr.y & (SCAN_B - 1)], 1);
        csr_src[p] = pr.x;
    }
}

// ================= layer 1: agg width 3 + small GEMM ==================

__global__ void k_agg3(const float* __restrict__ xs, const int* __restrict__ row_ptr,
                       const int* __restrict__ csr_src, const float* __restrict__ dinv,
                       float* __restrict__ out) {
    int n = blockIdx.x * blockDim.x + threadIdx.x;
    if (n >= N_NODES) return;
    int lo = row_ptr[n], hi = row_ptr[n + 1];
    float a0 = xs[n * 3 + 0], a1 = xs[n * 3 + 1], a2 = xs[n * 3 + 2];
    for (int i = lo; i < hi; ++i) {
        int s = csr_src[i];
        a0 += xs[s * 3 + 0];
        a1 += xs[s * 3 + 1];
        a2 += xs[s * 3 + 2];
    }
    float din = dinv[n];
    out[n * 3 + 0] = a0 * din;
    out[n * 3 + 1] = a1 * din;
    out[n * 3 + 2] = a2 * din;
}

template<int IN_W, int OUT_W, int NPB>
__global__ void k_node_gemm(const float* __restrict__ h, const float* __restrict__ W,
                            const float* __restrict__ b, const float* __restrict__ dinv,
                            unsigned short* __restrict__ hb) {
    __shared__ float rows[NPB][IN_W];
    int n0 = blockIdx.x * NPB;
    int j = threadIdx.x;                         // blockDim.x == OUT_W
    for (int t = j; t < NPB * IN_W; t += OUT_W) {
        int m = t / IN_W, k = t - m * IN_W;
        int n = n0 + m;
        rows[m][k] = (n < N_NODES) ? h[(size_t)n * IN_W + k] : 0.0f;
    }
    __syncthreads();
    float acc[NPB];
    float bj = b[j];
#pragma unroll
    for (int m = 0; m < NPB; ++m) acc[m] = bj;
#pragma unroll
    for (int k = 0; k < IN_W; ++k) {
        float wk = W[k * OUT_W + j];
#pragma unroll
        for (int m = 0; m < NPB; ++m) acc[m] += rows[m][k] * wk;
    }
#pragma unroll
    for (int m = 0; m < NPB; ++m) {
        int n = n0 + m;
        if (n < N_NODES)
            hb[(size_t)n * OUT_W + j] = f2bf(fmaxf(acc[m], 0.0f) * dinv[n]);
    }
}

// ================= aggregation (wave per node, multi-row dwordx4 gathers) =========

// width 64: row = 128 B = 8 chunks x 16 B -> 8 edge slots
__global__ void k_agg64(const unsigned short* __restrict__ hb, const int* __restrict__ row_ptr,
                        const int* __restrict__ csr_src, const float* __restrict__ dinv,
                        unsigned short* __restrict__ outb) {
    int wv = (blockIdx.x * blockDim.x + threadIdx.x) >> 6;
    int lane = threadIdx.x & 63;
    if (wv >= N_NODES) return;
    int q = lane & 7;           // 16B chunk in row
    int slot = lane >> 3;       // 0..7
    int lo = row_ptr[wv], hi = row_ptr[wv + 1];
    const uint4* hbv = (const uint4*)hb;       // row = 8 x uint4
    float acc[8];
#pragma unroll
    for (int i = 0; i < 8; ++i) acc[i] = 0.f;
    if (slot == 0) {                            // self-loop
        uint4 u = hbv[(size_t)wv * 8 + q];
        acc[0] += blo(u.x); acc[1] += bhi(u.x);
        acc[2] += blo(u.y); acc[3] += bhi(u.y);
        acc[4] += blo(u.z); acc[5] += bhi(u.z);
        acc[6] += blo(u.w); acc[7] += bhi(u.w);
    }
    for (int base = lo; base < hi; base += 32) {
#pragma unroll
        for (int k = 0; k < 4; ++k) {
            int e = base + k * 8 + slot;
            int ee = e < hi ? e : hi - 1;
            int s = csr_src[ee];
            uint4 u = hbv[(size_t)s * 8 + q];
            if (e < hi) {
                acc[0] += blo(u.x); acc[1] += bhi(u.x);
                acc[2] += blo(u.y); acc[3] += bhi(u.y);
                acc[4] += blo(u.z); acc[5] += bhi(u.z);
                acc[6] += blo(u.w); acc[7] += bhi(u.w);
            }
        }
    }
#pragma unroll
    for (int i = 0; i < 8; ++i) {
        acc[i] += __shfl_xor(acc[i], 8);
        acc[i] += __shfl_xor(acc[i], 16);
        acc[i] += __shfl_xor(acc[i], 32);
    }
    if (slot == 0) {
        float din = dinv[wv];
        uint4 w;
        w.x = (unsigned int)f2bf(acc[0] * din) | ((unsigned int)f2bf(acc[1] * din) << 16);
        w.y = (unsigned int)f2bf(acc[2] * din) | ((unsigned int)f2bf(acc[3] * din) << 16);
        w.z = (unsigned int)f2bf(acc[4] * din) | ((unsigned int)f2bf(acc[5] * din) << 16);
        w.w = (unsigned int)f2bf(acc[6] * din) | ((unsigned int)f2bf(acc[7] * din) << 16);
        ((uint4*)outb)[(size_t)wv * 8 + q] = w;
    }
}

// width 128: row = 256 B = 16 chunks x 16 B -> 4 edge slots
__global__ void k_agg128(const unsigned short* __restrict__ hb, const int* __restrict__ row_ptr,
                         const int* __restrict__ csr_src, const float* __restrict__ dinv,
                         unsigned short* __restrict__ outb) {
    int wv = (blockIdx.x * blockDim.x + threadIdx.x) >> 6;
    int lane = threadIdx.x & 63;
    if (wv >= N_NODES) return;
    int q = lane & 15;          // 16B chunk in row
    int slot = lane >> 4;       // 0..3
    int lo = row_ptr[wv], hi = row_ptr[wv + 1];
    const uint4* hbv = (const uint4*)hb;       // row = 16 x uint4
    float acc[8];
#pragma unroll
    for (int i = 0; i < 8; ++i) acc[i] = 0.f;
    if (slot == 0) {                            // self-loop
        uint4 u = hbv[(size_t)wv * 16 + q];
        acc[0] += blo(u.x); acc[1] += bhi(u.x);
        acc[2] += blo(u.y); acc[3] += bhi(u.y);
        acc[4] += blo(u.z); acc[5] += bhi(u.z);
        acc[6] += blo(u.w); acc[7] += bhi(u.w);
    }
    for (int base = lo; base < hi; base += 16) {
#pragma unroll
        for (int k = 0; k < 4; ++k) {
            int e = base + k * 4 + slot;
            int ee = e < hi ? e : hi - 1;
            int s = csr_src[ee];
            uint4 u = hbv[(size_t)s * 16 + q];
            if (e < hi) {
                acc[0] += blo(u.x); acc[1] += bhi(u.x);
                acc[2] += blo(u.y); acc[3] += bhi(u.y);
                acc[4] += blo(u.z); acc[5] += bhi(u.z);
                acc[6] += blo(u.w); acc[7] += bhi(u.w);
            }
        }
    }
#pragma unroll
    for (int i = 0; i < 8; ++i) {
        acc[i] += __shfl_xor(acc[i], 16);
        acc[i] += __shfl_xor(acc[i], 32);
    }
    if (slot == 0) {
        float din = dinv[wv];
        uint4 w;
        w.x = (unsigned int)f2bf(acc[0] * din) | ((unsigned int)f2bf(acc[1] * din) << 16);
        w.y = (unsigned int)f2bf(acc[2] * din) | ((unsigned int)f2bf(acc[3] * din) << 16);
        w.z = (unsigned int)f2bf(acc[4] * din) | ((unsigned int)f2bf(acc[5] * din) << 16);
        w.w = (unsigned int)f2bf(acc[6] * din) | ((unsigned int)f2bf(acc[7] * din) << 16);
        ((uint4*)outb)[(size_t)wv * 16 + q] = w;
    }
}

// ================= MFMA GEMM layer 2: [Nx64]bf16 @ [64x128] + b2 -> hb bf16 ======

__global__ __launch_bounds__(256) void k_gemm_l2_mfma(
    const unsigned short* __restrict__ Ab,   // [N][64] bf16
    const unsigned short* __restrict__ Wb,   // packed [8][128][8] bf16
    const float* __restrict__ b,
    const float* __restrict__ dinv,
    unsigned short* __restrict__ hb) {
    __shared__ float sC[64][128];
    int tid = threadIdx.x;
    int wave = tid >> 6, lane = tid & 63;
    int quad = lane >> 4, l16 = lane & 15;
    int n0 = blockIdx.x * 64;
    int arow = n0 + wave * 16 + l16;
    if (arow >= N_NODES) arow = N_NODES - 1;

    floatx4 acc[8];
#pragma unroll
    for (int t = 0; t < 8; ++t) acc[t] = (floatx4){0.f, 0.f, 0.f, 0.f};

#pragma unroll
    for (int ks = 0; ks < 2; ++ks) {
        short8 a = *(const short8*)(Ab + (size_t)arow * 64 + ks * 32 + quad * 8);
#pragma unroll
        for (int t = 0; t < 8; ++t) {
            short8 bf = *(const short8*)(Wb + (((ks * 4 + quad) * 128) + t * 16 + l16) * 8);
            acc[t] = __builtin_amdgcn_mfma_f32_16x16x32_bf16(a, bf, acc[t], 0, 0, 0);
        }
    }
#pragma unroll
    for (int t = 0; t < 8; ++t)
#pragma unroll
        for (int r = 0; r < 4; ++r)
            sC[wave * 16 + quad * 4 + r][t * 16 + l16] = acc[t][r];
    __syncthreads();
    int tn = tid >> 5, tj = tid & 31;
    float4 bv = *(const float4*)(b + tj * 4);
#pragma unroll
    for (int m = 0; m < 8; ++m) {
        int n = n0 + tn * 8 + m;
        if (n < N_NODES) {
            float di = dinv[n];
            unsigned short h0 = f2bf(fmaxf(sC[tn * 8 + m][tj * 4 + 0] + bv.x, 0.f) * di);
            unsigned short h1 = f2bf(fmaxf(sC[tn * 8 + m][tj * 4 + 1] + bv.y, 0.f) * di);
            unsigned short h2 = f2bf(fmaxf(sC[tn * 8 + m][tj * 4 + 2] + bv.z, 0.f) * di);
            unsigned short h3 = f2bf(fmaxf(sC[tn * 8 + m][tj * 4 + 3] + bv.w, 0.f) * di);
            uint2 w2;
            w2.x = (unsigned int)h0 | ((unsigned int)h1 << 16);
            w2.y = (unsigned int)h2 | ((unsigned int)h3 << 16);
            *(uint2*)(hb + (size_t)n * 128 + tj * 4) = w2;
        }
    }
}

// ======== MFMA GEMM layer 3: [Nx128]bf16 @ [128x128] + b3, relu, fused mean-pool ==

__global__ __launch_bounds__(256) void k_gemm_l3_mfma_pool(
    const unsigned short* __restrict__ Ab,   // [N][128] bf16
    const unsigned short* __restrict__ Wb,   // packed [16][128][8] bf16
    const float* __restrict__ b,
    const int* __restrict__ batch,
    float* __restrict__ pooled) {
    __shared__ float sC[64][128];
    __shared__ float red[8][128];
    __shared__ int sb[64];
    int tid = threadIdx.x;
    int wave = tid >> 6, lane = tid & 63;
    int quad = lane >> 4, l16 = lane & 15;
    int n0 = blockIdx.x * 64;
    int arow = n0 + wave * 16 + l16;
    if (arow >= N_NODES) arow = N_NODES - 1;

    floatx4 acc[8];
#pragma unroll
    for (int t = 0; t < 8; ++t) acc[t] = (floatx4){0.f, 0.f, 0.f, 0.f};

#pragma unroll
    for (int ks = 0; ks < 4; ++ks) {
        short8 a = *(const short8*)(Ab + (size_t)arow * 128 + ks * 32 + quad * 8);
#pragma unroll
        for (int t = 0; t < 8; ++t) {
            short8 bf = *(const short8*)(Wb + (((ks * 4 + quad) * 128) + t * 16 + l16) * 8);
            acc[t] = __builtin_amdgcn_mfma_f32_16x16x32_bf16(a, bf, acc[t], 0, 0, 0);
        }
    }
#pragma unroll
    for (int t = 0; t < 8; ++t) {
        float bc = b[t * 16 + l16];
#pragma unroll
        for (int r = 0; r < 4; ++r)
            sC[wave * 16 + quad * 4 + r][t * 16 + l16] = fmaxf(acc[t][r] + bc, 0.f);
    }
    if (tid < 64) {
        int n = n0 + tid;
        sb[tid] = (n < N_NODES) ? batch[n] : -1;
    }
    __syncthreads();
    int g0 = sb[0];
    int last = (n0 + 63 < N_NODES) ? (n0 + 63) : (N_NODES - 1);
    int g1 = batch[last];
    int tn = tid >> 5, tj = tid & 31;
    for (int g = g0; g <= g1; ++g) {
        float p0 = 0.f, p1 = 0.f, p2 = 0.f, p3 = 0.f;
#pragma unroll
        for (int m = 0; m < 8; ++m) {
            if (sb[tn * 8 + m] == g) {
                p0 += sC[tn * 8 + m][tj * 4 + 0];
                p1 += sC[tn * 8 + m][tj * 4 + 1];
                p2 += sC[tn * 8 + m][tj * 4 + 2];
                p3 += sC[tn * 8 + m][tj * 4 + 3];
            }
        }
        red[tn][tj * 4 + 0] = p0;
        red[tn][tj * 4 + 1] = p1;
        red[tn][tj * 4 + 2] = p2;
        red[tn][tj * 4 + 3] = p3;
        __syncthreads();
        if (tid < 128) {
            float s = 0.f;
#pragma unroll
            for (int r = 0; r < 8; ++r) s += red[r][tid];
            atomicAdd(&pooled[g * 128 + tid], s);
        }
        __syncthreads();
    }
}

// ================= final FC head =================

__device__ __forceinline__ int lower_bound_batch(const int* __restrict__ batch, int val) {
    int lo = 0, hi = N_NODES;
    while (lo < hi) {
        int mid = (lo + hi) >> 1;
        if (batch[mid] < val) lo = mid + 1; else hi = mid;
    }
    return lo;
}

__global__ void k_fc(const float* __restrict__ pooled, const int* __restrict__ batch,
                     const float* __restrict__ Wf1, const float* __restrict__ bf1,
                     const float* __restrict__ Wf2, const float* __restrict__ bf2,
                     float* __restrict__ out) {
    __shared__ float sp[128];
    __shared__ float sh1[64];
    int g = blockIdx.x;
    int t = threadIdx.x;             // 128
    int lo = lower_bound_batch(batch, g);
    int hi = lower_bound_batch(batch, g + 1);
    float inv = 1.0f / fmaxf((float)(hi - lo), 1.0f);
    sp[t] = pooled[g * 128 + t] * inv;
    __syncthreads();
    if (t < 64) {
        float acc = bf1[t];
#pragma unroll 8
        for (int k = 0; k < 128; ++k) acc += sp[k] * Wf1[k * 64 + t];
        sh1[t] = fmaxf(acc, 0.0f);
    }
    __syncthreads();
    if (t < 10) {
        float acc = bf2[t];
#pragma unroll 8
        for (int k = 0; k < 64; ++k) acc += sh1[k] * Wf2[k * 10 + t];
        out[g * 10 + t] = acc;
    }
}

extern "C" void kernel_launch(void* const* d_in, const int* in_sizes, int n_in,
                              void* d_out, int out_size, void* d_ws, size_t ws_size,
                              hipStream_t stream) {
    const float* x     = (const float*)d_in[0];
    const int*   ei    = (const int*)d_in[1];
    const int*   batch = (const int*)d_in[2];
    const float* W1  = (const float*)d_in[3];
    const float* b1  = (const float*)d_in[4];
    const float* W2  = (const float*)d_in[5];
    const float* b2  = (const float*)d_in[6];
    const float* W3  = (const float*)d_in[7];
    const float* b3  = (const float*)d_in[8];
    const float* Wf1 = (const float*)d_in[9];
    const float* bf1 = (const float*)d_in[10];
    const float* Wf2 = (const float*)d_in[11];
    const float* bf2 = (const float*)d_in[12];
    float* out = (float*)d_out;

    const int* src = ei;              // edge_index[0]
    const int* dst = ei + N_EDGES;    // edge_index[1]

    // workspace layout
    float* dinv   = (float*)d_ws;                      // N
    int*   bcnt   = (int*)(dinv + N_NODES);            // 256
    int*   bstart = bcnt + 256;                        // 257
    int*   bcursor= bstart + 257;                      // 256
    int*   row_ptr= bcursor + 256;                     // N+1
    int*   csr_src= row_ptr + N_NODES + 1;             // N_EDGES
    size_t o1 = (size_t)(csr_src + N_EDGES) - (size_t)d_ws;
    o1 = (o1 + 7) & ~(size_t)7;
    int2*  bpair  = (int2*)((char*)d_ws + o1);         // N_EDGES int2
    float* xs     = (float*)(bpair + N_EDGES);         // N*3
    float* a3     = xs + (size_t)N_NODES * 3;          // N*3 (agg3 out)
    unsigned short* Wb2 = (unsigned short*)(a3 + (size_t)N_NODES * 3);  // 8192
    unsigned short* Wb3 = Wb2 + 64 * 128;                               // 16384
    size_t ofs = (size_t)(Wb3 + 128 * 128) - (size_t)d_ws;
    ofs = (ofs + 15) & ~(size_t)15;
    unsigned short* bufA = (unsigned short*)((char*)d_ws + ofs);        // N*128 bf16 (agg out)
    unsigned short* hb   = bufA + (size_t)N_NODES * 128;                // N*128 bf16 (gemm out)
    float* pooled = (float*)(hb + (size_t)N_NODES * 128);               // G*128

    const int TB = 256;
    const int GEMM_BLKS = (N_NODES + 63) / 64;
    const int PREP_N = 256 + N_GRAPHS * 128 + 64 * 128 + 128 * 128;
    const int BIN_BLKS = (N_EDGES + FILL_E - 1) / FILL_E;

    // ---- prep + bucketed CSR build ----
    k_prep<<<(PREP_N + TB - 1) / TB, TB, 0, stream>>>(bcnt, pooled, W2, W3, Wb2, Wb3);
    k_bhist<<<256, 256, 0, stream>>>(dst, bcnt);
    k_bscan<<<1, 256, 0, stream>>>(bcnt, bstart, bcursor);
    k_binfill<<<BIN_BLKS, 256, 0, stream>>>(src, dst, bcursor, bpair);
    k_build<<<SCAN_NBLK, 256, 0, stream>>>(bpair, bstart, row_ptr, csr_src, dinv, x, xs);

    // ---- layer 1: agg3(xs) @ W1 + b1 -> hb = bf16(dinv*relu) ----
    k_agg3<<<(N_NODES + TB - 1) / TB, TB, 0, stream>>>(xs, row_ptr, csr_src, dinv, a3);
    k_node_gemm<3, 64, 4><<<(N_NODES + 3) / 4, 64, 0, stream>>>(a3, W1, b1, dinv, hb);

    // ---- layer 2: agg64(hb) -> bufA bf16; MFMA @ W2 + b2 -> hb bf16 ----
    k_agg64<<<(N_NODES * 64 + TB - 1) / TB, TB, 0, stream>>>(hb, row_ptr, csr_src, dinv, bufA);
    k_gemm_l2_mfma<<<GEMM_BLKS, 256, 0, stream>>>(bufA, Wb2, b2, dinv, hb);

    // ---- layer 3: agg128(hb) -> bufA bf16; MFMA @ W3 + b3, relu, fused pool ----
    k_agg128<<<(N_NODES * 64 + TB - 1) / TB, TB, 0, stream>>>(hb, row_ptr, csr_src, dinv, bufA);
    k_gemm_l3_mfma_pool<<<GEMM_BLKS, 256, 0, stream>>>(bufA, Wb3, b3, batch, pooled);

    // ---- FC head ----
    k_fc<<<N_GRAPHS, 128, 0, stream>>>(pooled, batch, Wf1, bf1, Wf2, bf2, out);
}

// Round 15
// 237.726 us; speedup vs baseline: 1.2894x; 1.0033x over previous
//
#include <hip/hip_runtime.h>

#define N_NODES 50000
#define N_EDGES 800000
#define N_GRAPHS 64
#define SCAN_B 256
#define SCAN_NBLK ((N_NODES + SCAN_B - 1) / SCAN_B)   // 196 buckets of 256 nodes
#define FILL_E 2048

typedef __attribute__((ext_vector_type(8))) short short8;
typedef __attribute__((ext_vector_type(4))) float floatx4;

// fp32 -> bf16 round-to-nearest-even
__device__ __forceinline__ unsigned short f2bf(float f) {
    unsigned int u = __float_as_uint(f);
    u += 0x7FFFu + ((u >> 16) & 1u);
    return (unsigned short)(u >> 16);
}
__device__ __forceinline__ float bf2f(unsigned short h) {
    return __uint_as_float(((unsigned int)h) << 16);
}
__device__ __forceinline__ float blo(unsigned int u) { return __uint_as_float(u << 16); }
__device__ __forceinline__ float bhi(unsigned int u) { return __uint_as_float(u & 0xffff0000u); }

// ===== hist + prep: per-block private bucket histogram (no pre-zero, no global
// atomics) + pooled zero + W2/W3 bf16 B-frag casts.  Grid = 256 blocks. =====

__global__ __launch_bounds__(256) void k_hist_prep(const int* __restrict__ dst,
                                                   int* __restrict__ bins_global,
                                                   float* pooled,
                                                   const float* __restrict__ W2,
                                                   const float* __restrict__ W3,
                                                   unsigned short* Wb2, unsigned short* Wb3) {
    __shared__ int bins[SCAN_NBLK];
    int t = threadIdx.x;
    for (int i = t; i < SCAN_NBLK; i += 256) bins[i] = 0;
    __syncthreads();
    int gid = blockIdx.x * 256 + t;
    // prep work (single pass: 65536 threads >= 32768 items)
    if (gid < N_GRAPHS * 128) pooled[gid] = 0.0f;
    int k = gid - N_GRAPHS * 128;
    if (k >= 0 && k < 64 * 128) {
        int kk = k >> 7, n = k & 127;
        Wb2[(((kk >> 3) * 128) + n) * 8 + (kk & 7)] = f2bf(W2[k]);
    }
    int l = gid - N_GRAPHS * 128 - 64 * 128;
    if (l >= 0 && l < 128 * 128) {
        int kk = l >> 7, n = l & 127;
        Wb3[(((kk >> 3) * 128) + n) * 8 + (kk & 7)] = f2bf(W3[l]);
    }
    // bucket histogram (int4 loads, LDS atomics only)
    const int stride = 256 * 256;
    for (int i4 = gid; i4 < N_EDGES / 4; i4 += stride) {
        int4 d = ((const int4*)dst)[i4];
        atomicAdd(&bins[d.x >> 8], 1);
        atomicAdd(&bins[d.y >> 8], 1);
        atomicAdd(&bins[d.z >> 8], 1);
        atomicAdd(&bins[d.w >> 8], 1);
    }
    __syncthreads();
    for (int i = t; i < SCAN_NBLK; i += 256)
        bins_global[blockIdx.x * SCAN_NBLK + i] = bins[i];
}

// single block: column-sum the 256 slices, exclusive scan -> bstart (257), bcursor
__global__ __launch_bounds__(256) void k_bscan(const int* __restrict__ bins_global,
                                               int* bstart, int* bcursor) {
    __shared__ int s[256];
    int t = threadIdx.x;
    int c = 0;
    if (t < SCAN_NBLK)
        for (int r = 0; r < 256; ++r) c += bins_global[r * SCAN_NBLK + t];
    s[t] = c;
    __syncthreads();
    for (int off = 1; off < 256; off <<= 1) {
        int v = (t >= off) ? s[t - off] : 0;
        __syncthreads();
        s[t] += v;
        __syncthreads();
    }
    int excl = s[t] - c;
    bstart[t] = excl;                 // t >= SCAN_NBLK -> total = N_EDGES
    bcursor[t] = excl;
    if (t == 255) bstart[256] = s[255];
}

// LDS counting-sort 2048 edges by bucket (dst>>8), flush contiguous runs
__global__ __launch_bounds__(256) void k_binfill(const int* __restrict__ src,
                                                 const int* __restrict__ dst,
                                                 int* bcursor, int2* __restrict__ bpair) {
    __shared__ int cnt[SCAN_B];
    __shared__ int sc[SCAN_B];
    __shared__ int base[SCAN_B];
    __shared__ int delta[SCAN_B];
    __shared__ int ofs[SCAN_B];
    __shared__ int2 stage[FILL_E];             // 16 KB
    __shared__ unsigned char bk[FILL_E];       // 2 KB
    int tid = threadIdx.x;
    int e0 = blockIdx.x * FILL_E + tid * 8;
    cnt[tid] = 0; ofs[tid] = 0;
    __syncthreads();
    int s[8], d[8], bb[8];
    bool active = e0 < N_EDGES;                // tails are multiples of 8
    if (active) {
        int4 sa = *(const int4*)(src + e0);
        int4 sb = *(const int4*)(src + e0 + 4);
        int4 da = *(const int4*)(dst + e0);
        int4 db = *(const int4*)(dst + e0 + 4);
        s[0]=sa.x; s[1]=sa.y; s[2]=sa.z; s[3]=sa.w;
        s[4]=sb.x; s[5]=sb.y; s[6]=sb.z; s[7]=sb.w;
        d[0]=da.x; d[1]=da.y; d[2]=da.z; d[3]=da.w;
        d[4]=db.x; d[5]=db.y; d[6]=db.z; d[7]=db.w;
#pragma unroll
        for (int k = 0; k < 8; ++k) {
            bb[k] = d[k] >> 8;
            atomicAdd(&cnt[bb[k]], 1);
        }
    }
    __syncthreads();
    int c = cnt[tid];
    sc[tid] = c;
    __syncthreads();
    for (int off = 1; off < SCAN_B; off <<= 1) {
        int v = (tid >= off) ? sc[tid - off] : 0;
        __syncthreads();
        sc[tid] += v;
        __syncthreads();
    }
    base[tid] = sc[tid] - c;                   // exclusive scan
    if (c > 0) delta[tid] = atomicAdd(&bcursor[tid], c) - base[tid];
    __syncthreads();
    if (active) {
#pragma unroll
        for (int k = 0; k < 8; ++k) {
            int p = base[bb[k]] + atomicAdd(&ofs[bb[k]], 1);
            stage[p] = make_int2(s[k], d[k]);
            bk[p] = (unsigned char)bb[k];
        }
    }
    __syncthreads();
    int total = base[SCAN_B - 1] + cnt[SCAN_B - 1];
    for (int i = tid; i < total; i += 256)
        bpair[delta[bk[i]] + i] = stage[i];
}

// one block per bucket: LDS node-histogram -> LDS scan -> row_ptr/dinv/xs -> scatter
__global__ __launch_bounds__(256) void k_build(const int2* __restrict__ bpair,
                                               const int* __restrict__ bstart,
                                               int* row_ptr, int* __restrict__ csr_src,
                                               float* dinv,
                                               const float* __restrict__ x,
                                               float* __restrict__ xs) {
    __shared__ int cnt[SCAN_B];
    __shared__ int sc[SCAN_B];
    __shared__ int cur[SCAN_B];
    int b = blockIdx.x, t = threadIdx.x;
    int start = bstart[b], end = bstart[b + 1];
    cnt[t] = 0;
    __syncthreads();
    for (int i = start + t; i < end; i += 256)
        atomicAdd(&cnt[bpair[i].y & (SCAN_B - 1)], 1);
    __syncthreads();
    int c = cnt[t];
    sc[t] = c;
    __syncthreads();
    for (int off = 1; off < SCAN_B; off <<= 1) {
        int v = (t >= off) ? sc[t - off] : 0;
        __syncthreads();
        sc[t] += v;
        __syncthreads();
    }
    int pos = start + sc[t] - c;               // node's CSR start
    cur[t] = pos;
    int n = b * SCAN_B + t;
    if (n < N_NODES) {
        row_ptr[n] = pos;
        float di = rsqrtf((float)(c + 1));
        dinv[n] = di;
        xs[n * 3 + 0] = x[n * 3 + 0] * di;
        xs[n * 3 + 1] = x[n * 3 + 1] * di;
        xs[n * 3 + 2] = x[n * 3 + 2] * di;
    }
    if (n == N_NODES) row_ptr[N_NODES] = N_EDGES;
    __syncthreads();
    for (int i = start + t; i < end; i += 256) {
        int2 pr = bpair[i];
        int p = atomicAdd(&cur[pr.y & (SCAN_B - 1)], 1);
        csr_src[p] = pr.x;
    }
}

// ===== layer 1 fused: agg3 (thread-per-node, xs L2-resident) + 3->64 GEMM + bias,
// epilogue bf16(dinv*relu). W1/b1 staged in LDS. =====

__global__ __launch_bounds__(256) void k_l1_fused(
    const float* __restrict__ xs, const int* __restrict__ row_ptr,
    const int* __restrict__ csr_src, const float* __restrict__ dinv,
    const float* __restrict__ W1, const float* __restrict__ b1,
    unsigned short* __restrict__ hb) {
    __shared__ float sW[192];    // W1 [3][64] row-major
    __shared__ float sb[64];
    int t = threadIdx.x;
    if (t < 192) sW[t] = W1[t];
    if (t < 64) sb[t] = b1[t];
    __syncthreads();
    int n = blockIdx.x * 256 + t;
    if (n >= N_NODES) return;
    int lo = row_ptr[n], hi = row_ptr[n + 1];
    float a0 = xs[n * 3 + 0], a1 = xs[n * 3 + 1], a2 = xs[n * 3 + 2];
    for (int i = lo; i < hi; ++i) {
        int s = csr_src[i];
        a0 += xs[s * 3 + 0];
        a1 += xs[s * 3 + 1];
        a2 += xs[s * 3 + 2];
    }
    float din = dinv[n];
    a0 *= din; a1 *= din; a2 *= din;
    uint4* row = (uint4*)(hb + (size_t)n * 64);
#pragma unroll
    for (int j0 = 0; j0 < 64; j0 += 8) {
        unsigned int h[4];
#pragma unroll
        for (int k = 0; k < 4; ++k) {
            int j = j0 + 2 * k;
            float v0 = a0 * sW[j] + a1 * sW[64 + j] + a2 * sW[128 + j] + sb[j];
            float v1 = a0 * sW[j + 1] + a1 * sW[64 + j + 1] + a2 * sW[128 + j + 1] + sb[j + 1];
            h[k] = (unsigned int)f2bf(fmaxf(v0, 0.f) * din)
                 | ((unsigned int)f2bf(fmaxf(v1, 0.f) * din) << 16);
        }
        uint4 w; w.x = h[0]; w.y = h[1]; w.z = h[2]; w.w = h[3];
        row[j0 >> 3] = w;
    }
}

// ================= aggregation (wave per node, multi-row dwordx4 gathers) =========

// width 64: row = 128 B = 8 chunks x 16 B -> 8 edge slots
__global__ void k_agg64(const unsigned short* __restrict__ hb, const int* __restrict__ row_ptr,
                        const int* __restrict__ csr_src, const float* __restrict__ dinv,
                        unsigned short* __restrict__ outb) {
    int wv = (blockIdx.x * blockDim.x + threadIdx.x) >> 6;
    int lane = threadIdx.x & 63;
    if (wv >= N_NODES) return;
    int q = lane & 7;           // 16B chunk in row
    int slot = lane >> 3;       // 0..7
    int lo = row_ptr[wv], hi = row_ptr[wv + 1];
    const uint4* hbv = (const uint4*)hb;       // row = 8 x uint4
    float acc[8];
#pragma unroll
    for (int i = 0; i < 8; ++i) acc[i] = 0.f;
    if (slot == 0) {                            // self-loop
        uint4 u = hbv[(size_t)wv * 8 + q];
        acc[0] += blo(u.x); acc[1] += bhi(u.x);
        acc[2] += blo(u.y); acc[3] += bhi(u.y);
        acc[4] += blo(u.z); acc[5] += bhi(u.z);
        acc[6] += blo(u.w); acc[7] += bhi(u.w);
    }
    for (int base = lo; base < hi; base += 32) {
#pragma unroll
        for (int k = 0; k < 4; ++k) {
            int e = base + k * 8 + slot;
            int ee = e < hi ? e : hi - 1;
            int s = csr_src[ee];
            uint4 u = hbv[(size_t)s * 8 + q];
            if (e < hi) {
                acc[0] += blo(u.x); acc[1] += bhi(u.x);
                acc[2] += blo(u.y); acc[3] += bhi(u.y);
                acc[4] += blo(u.z); acc[5] += bhi(u.z);
                acc[6] += blo(u.w); acc[7] += bhi(u.w);
            }
        }
    }
#pragma unroll
    for (int i = 0; i < 8; ++i) {
        acc[i] += __shfl_xor(acc[i], 8);
        acc[i] += __shfl_xor(acc[i], 16);
        acc[i] += __shfl_xor(acc[i], 32);
    }
    if (slot == 0) {
        float din = dinv[wv];
        uint4 w;
        w.x = (unsigned int)f2bf(acc[0] * din) | ((unsigned int)f2bf(acc[1] * din) << 16);
        w.y = (unsigned int)f2bf(acc[2] * din) | ((unsigned int)f2bf(acc[3] * din) << 16);
        w.z = (unsigned int)f2bf(acc[4] * din) | ((unsigned int)f2bf(acc[5] * din) << 16);
        w.w = (unsigned int)f2bf(acc[6] * din) | ((unsigned int)f2bf(acc[7] * din) << 16);
        ((uint4*)outb)[(size_t)wv * 8 + q] = w;
    }
}

// width 128: row = 256 B = 16 chunks x 16 B -> 4 edge slots
__global__ void k_agg128(const unsigned short* __restrict__ hb, const int* __restrict__ row_ptr,
                         const int* __restrict__ csr_src, const float* __restrict__ dinv,
                         unsigned short* __restrict__ outb) {
    int wv = (blockIdx.x * blockDim.x + threadIdx.x) >> 6;
    int lane = threadIdx.x & 63;
    if (wv >= N_NODES) return;
    int q = lane & 15;          // 16B chunk in row
    int slot = lane >> 4;       // 0..3
    int lo = row_ptr[wv], hi = row_ptr[wv + 1];
    const uint4* hbv = (const uint4*)hb;       // row = 16 x uint4
    float acc[8];
#pragma unroll
    for (int i = 0; i < 8; ++i) acc[i] = 0.f;
    if (slot == 0) {                            // self-loop
        uint4 u = hbv[(size_t)wv * 16 + q];
        acc[0] += blo(u.x); acc[1] += bhi(u.x);
        acc[2] += blo(u.y); acc[3] += bhi(u.y);
        acc[4] += blo(u.z); acc[5] += bhi(u.z);
        acc[6] += blo(u.w); acc[7] += bhi(u.w);
    }
    for (int base = lo; base < hi; base += 16) {
#pragma unroll
        for (int k = 0; k < 4; ++k) {
            int e = base + k * 4 + slot;
            int ee = e < hi ? e : hi - 1;
            int s = csr_src[ee];
            uint4 u = hbv[(size_t)s * 16 + q];
            if (e < hi) {
                acc[0] += blo(u.x); acc[1] += bhi(u.x);
                acc[2] += blo(u.y); acc[3] += bhi(u.y);
                acc[4] += blo(u.z); acc[5] += bhi(u.z);
                acc[6] += blo(u.w); acc[7] += bhi(u.w);
            }
        }
    }
#pragma unroll
    for (int i = 0; i < 8; ++i) {
        acc[i] += __shfl_xor(acc[i], 16);
        acc[i] += __shfl_xor(acc[i], 32);
    }
    if (slot == 0) {
        float din = dinv[wv];
        uint4 w;
        w.x = (unsigned int)f2bf(acc[0] * din) | ((unsigned int)f2bf(acc[1] * din) << 16);
        w.y = (unsigned int)f2bf(acc[2] * din) | ((unsigned int)f2bf(acc[3] * din) << 16);
        w.z = (unsigned int)f2bf(acc[4] * din) | ((unsigned int)f2bf(acc[5] * din) << 16);
        w.w = (unsigned int)f2bf(acc[6] * din) | ((unsigned int)f2bf(acc[7] * din) << 16);
        ((uint4*)outb)[(size_t)wv * 16 + q] = w;
    }
}

// ================= MFMA GEMM layer 2: [Nx64]bf16 @ [64x128] + b2 -> hb bf16 ======

__global__ __launch_bounds__(256) void k_gemm_l2_mfma(
    const unsigned short* __restrict__ Ab,   // [N][64] bf16
    const unsigned short* __restrict__ Wb,   // packed [8][128][8] bf16
    const float* __restrict__ b,
    const float* __restrict__ dinv,
    unsigned short* __restrict__ hb) {
    __shared__ float sC[64][128];
    int tid = threadIdx.x;
    int wave = tid >> 6, lane = tid & 63;
    int quad = lane >> 4, l16 = lane & 15;
    int n0 = blockIdx.x * 64;
    int arow = n0 + wave * 16 + l16;
    if (arow >= N_NODES) arow = N_NODES - 1;

    floatx4 acc[8];
#pragma unroll
    for (int t = 0; t < 8; ++t) acc[t] = (floatx4){0.f, 0.f, 0.f, 0.f};

#pragma unroll
    for (int ks = 0; ks < 2; ++ks) {
        short8 a = *(const short8*)(Ab + (size_t)arow * 64 + ks * 32 + quad * 8);
#pragma unroll
        for (int t = 0; t < 8; ++t) {
            short8 bf = *(const short8*)(Wb + (((ks * 4 + quad) * 128) + t * 16 + l16) * 8);
            acc[t] = __builtin_amdgcn_mfma_f32_16x16x32_bf16(a, bf, acc[t], 0, 0, 0);
        }
    }
#pragma unroll
    for (int t = 0; t < 8; ++t)
#pragma unroll
        for (int r = 0; r < 4; ++r)
            sC[wave * 16 + quad * 4 + r][t * 16 + l16] = acc[t][r];
    __syncthreads();
    int tn = tid >> 5, tj = tid & 31;
    float4 bv = *(const float4*)(b + tj * 4);
#pragma unroll
    for (int m = 0; m < 8; ++m) {
        int n = n0 + tn * 8 + m;
        if (n < N_NODES) {
            float di = dinv[n];
            unsigned short h0 = f2bf(fmaxf(sC[tn * 8 + m][tj * 4 + 0] + bv.x, 0.f) * di);
            unsigned short h1 = f2bf(fmaxf(sC[tn * 8 + m][tj * 4 + 1] + bv.y, 0.f) * di);
            unsigned short h2 = f2bf(fmaxf(sC[tn * 8 + m][tj * 4 + 2] + bv.z, 0.f) * di);
            unsigned short h3 = f2bf(fmaxf(sC[tn * 8 + m][tj * 4 + 3] + bv.w, 0.f) * di);
            uint2 w2;
            w2.x = (unsigned int)h0 | ((unsigned int)h1 << 16);
            w2.y = (unsigned int)h2 | ((unsigned int)h3 << 16);
            *(uint2*)(hb + (size_t)n * 128 + tj * 4) = w2;
        }
    }
}

// ======== MFMA GEMM layer 3: [Nx128]bf16 @ [128x128] + b3, relu, fused mean-pool ==

__global__ __launch_bounds__(256) void k_gemm_l3_mfma_pool(
    const unsigned short* __restrict__ Ab,   // [N][128] bf16
    const unsigned short* __restrict__ Wb,   // packed [16][128][8] bf16
    const float* __restrict__ b,
    const int* __restrict__ batch,
    float* __restrict__ pooled) {
    __shared__ float sC[64][128];
    __shared__ float red[8][128];
    __shared__ int sb[64];
    int tid = threadIdx.x;
    int wave = tid >> 6, lane = tid & 63;
    int quad = lane >> 4, l16 = lane & 15;
    int n0 = blockIdx.x * 64;
    int arow = n0 + wave * 16 + l16;
    if (arow >= N_NODES) arow = N_NODES - 1;

    floatx4 acc[8];
#pragma unroll
    for (int t = 0; t < 8; ++t) acc[t] = (floatx4){0.f, 0.f, 0.f, 0.f};

#pragma unroll
    for (int ks = 0; ks < 4; ++ks) {
        short8 a = *(const short8*)(Ab + (size_t)arow * 128 + ks * 32 + quad * 8);
#pragma unroll
        for (int t = 0; t < 8; ++t) {
            short8 bf = *(const short8*)(Wb + (((ks * 4 + quad) * 128) + t * 16 + l16) * 8);
            acc[t] = __builtin_amdgcn_mfma_f32_16x16x32_bf16(a, bf, acc[t], 0, 0, 0);
        }
    }
#pragma unroll
    for (int t = 0; t < 8; ++t) {
        float bc = b[t * 16 + l16];
#pragma unroll
        for (int r = 0; r < 4; ++r)
            sC[wave * 16 + quad * 4 + r][t * 16 + l16] = fmaxf(acc[t][r] + bc, 0.f);
    }
    if (tid < 64) {
        int n = n0 + tid;
        sb[tid] = (n < N_NODES) ? batch[n] : -1;
    }
    __syncthreads();
    int g0 = sb[0];
    int last = (n0 + 63 < N_NODES) ? (n0 + 63) : (N_NODES - 1);
    int g1 = batch[last];
    int tn = tid >> 5, tj = tid & 31;
    for (int g = g0; g <= g1; ++g) {
        float p0 = 0.f, p1 = 0.f, p2 = 0.f, p3 = 0.f;
#pragma unroll
        for (int m = 0; m < 8; ++m) {
            if (sb[tn * 8 + m] == g) {
                p0 += sC[tn * 8 + m][tj * 4 + 0];
                p1 += sC[tn * 8 + m][tj * 4 + 1];
                p2 += sC[tn * 8 + m][tj * 4 + 2];
                p3 += sC[tn * 8 + m][tj * 4 + 3];
            }
        }
        red[tn][tj * 4 + 0] = p0;
        red[tn][tj * 4 + 1] = p1;
        red[tn][tj * 4 + 2] = p2;
        red[tn][tj * 4 + 3] = p3;
        __syncthreads();
        if (tid < 128) {
            float s = 0.f;
#pragma unroll
            for (int r = 0; r < 8; ++r) s += red[r][tid];
            atomicAdd(&pooled[g * 128 + tid], s);
        }
        __syncthreads();
    }
}

// ================= final FC head =================

__device__ __forceinline__ int lower_bound_batch(const int* __restrict__ batch, int val) {
    int lo = 0, hi = N_NODES;
    while (lo < hi) {
        int mid = (lo + hi) >> 1;
        if (batch[mid] < val) lo = mid + 1; else hi = mid;
    }
    return lo;
}

__global__ void k_fc(const float* __restrict__ pooled, const int* __restrict__ batch,
                     const float* __restrict__ Wf1, const float* __restrict__ bf1,
                     const float* __restrict__ Wf2, const float* __restrict__ bf2,
                     float* __restrict__ out) {
    __shared__ float sp[128];
    __shared__ float sh1[64];
    int g = blockIdx.x;
    int t = threadIdx.x;             // 128
    int lo = lower_bound_batch(batch, g);
    int hi = lower_bound_batch(batch, g + 1);
    float inv = 1.0f / fmaxf((float)(hi - lo), 1.0f);
    sp[t] = pooled[g * 128 + t] * inv;
    __syncthreads();
    if (t < 64) {
        float acc = bf1[t];
#pragma unroll 8
        for (int k = 0; k < 128; ++k) acc += sp[k] * Wf1[k * 64 + t];
        sh1[t] = fmaxf(acc, 0.0f);
    }
    __syncthreads();
    if (t < 10) {
        float acc = bf2[t];
#pragma unroll 8
        for (int k = 0; k < 64; ++k) acc += sh1[k] * Wf2[k * 10 + t];
        out[g * 10 + t] = acc;
    }
}

extern "C" void kernel_launch(void* const* d_in, const int* in_sizes, int n_in,
                              void* d_out, int out_size, void* d_ws, size_t ws_size,
                              hipStream_t stream) {
    const float* x     = (const float*)d_in[0];
    const int*   ei    = (const int*)d_in[1];
    const int*   batch = (const int*)d_in[2];
    const float* W1  = (const float*)d_in[3];
    const float* b1  = (const float*)d_in[4];
    const float* W2  = (const float*)d_in[5];
    const float* b2  = (const float*)d_in[6];
    const float* W3  = (const float*)d_in[7];
    const float* b3  = (const float*)d_in[8];
    const float* Wf1 = (const float*)d_in[9];
    const float* bf1 = (const float*)d_in[10];
    const float* Wf2 = (const float*)d_in[11];
    const float* bf2 = (const float*)d_in[12];
    float* out = (float*)d_out;

    const int* src = ei;              // edge_index[0]
    const int* dst = ei + N_EDGES;    // edge_index[1]

    // workspace layout
    float* dinv      = (float*)d_ws;                   // N
    int* bins_global = (int*)(dinv + N_NODES);         // 256 * SCAN_NBLK
    int* bstart      = bins_global + 256 * SCAN_NBLK;  // 257
    int* bcursor     = bstart + 257;                   // 256
    int* row_ptr     = bcursor + 256;                  // N+1
    int* csr_src     = row_ptr + N_NODES + 1;          // N_EDGES
    size_t o1 = (size_t)(csr_src + N_EDGES) - (size_t)d_ws;
    o1 = (o1 + 7) & ~(size_t)7;
    int2* bpair      = (int2*)((char*)d_ws + o1);      // N_EDGES int2
    float* xs        = (float*)(bpair + N_EDGES);      // N*3
    unsigned short* Wb2 = (unsigned short*)(xs + (size_t)N_NODES * 3);  // 8192
    unsigned short* Wb3 = Wb2 + 64 * 128;                               // 16384
    size_t ofs = (size_t)(Wb3 + 128 * 128) - (size_t)d_ws;
    ofs = (ofs + 15) & ~(size_t)15;
    unsigned short* bufA = (unsigned short*)((char*)d_ws + ofs);        // N*128 bf16 (agg out)
    unsigned short* hb   = bufA + (size_t)N_NODES * 128;                // N*128 bf16 (gemm out)
    float* pooled = (float*)(hb + (size_t)N_NODES * 128);               // G*128

    const int TB = 256;
    const int GEMM_BLKS = (N_NODES + 63) / 64;
    const int BIN_BLKS = (N_EDGES + FILL_E - 1) / FILL_E;

    // ---- hist+prep, scan, bucketed sort, CSR build ----
    k_hist_prep<<<256, 256, 0, stream>>>(dst, bins_global, pooled, W2, W3, Wb2, Wb3);
    k_bscan<<<1, 256, 0, stream>>>(bins_global, bstart, bcursor);
    k_binfill<<<BIN_BLKS, 256, 0, stream>>>(src, dst, bcursor, bpair);
    k_build<<<SCAN_NBLK, 256, 0, stream>>>(bpair, bstart, row_ptr, csr_src, dinv, x, xs);

    // ---- layer 1 fused: agg3 + GEMM -> hb = bf16(dinv*relu) ----
    k_l1_fused<<<SCAN_NBLK, 256, 0, stream>>>(xs, row_ptr, csr_src, dinv, W1, b1, hb);

    // ---- layer 2: agg64(hb) -> bufA bf16; MFMA @ W2 + b2 -> hb bf16 ----
    k_agg64<<<(N_NODES * 64 + TB - 1) / TB, TB, 0, stream>>>(hb, row_ptr, csr_src, dinv, bufA);
    k_gemm_l2_mfma<<<GEMM_BLKS, 256, 0, stream>>>(bufA, Wb2, b2, dinv, hb);

    // ---- layer 3: agg128(hb) -> bufA bf16; MFMA @ W3 + b3, relu, fused pool ----
    k_agg128<<<(N_NODES * 64 + TB - 1) / TB, TB, 0, stream>>>(hb, row_ptr, csr_src, dinv, bufA);
    k_gemm_l3_mfma_pool<<<GEMM_BLKS, 256, 0, stream>>>(bufA, Wb3, b3, batch, pooled);

    // ---- FC head ----
    k_fc<<<N_GRAPHS, 128, 0, stream>>>(pooled, batch, Wf1, bf1, Wf2, bf2, out);
}